// Round 4
// baseline (381.950 us; speedup 1.0000x reference)
//
#include <hip/hip_runtime.h>
#include <math.h>

#define BB 64
#define TT 256
#define VV 256
#define SLABS 321   // s = t + v/4 in [0,318]; +2 pad so clamped prefetch stays in-bounds

// logaddexp, branchless, robust to -inf operands
__device__ __forceinline__ float lae(float x, float y) {
    float m = fmaxf(x, y);
    float n = fminf(x, y);
    float d = (n == -INFINITY) ? -INFINITY : (n - m);
    return m + __logf(1.0f + __expf(d));
}

// Kernel 1: log_softmax over C=4; writes canonical scores (output 0) and,
// optionally, a diagonal-major copy D[b][s][v] (s = t + v/4) for k_dp.
__global__ void k_prep(const float4* __restrict__ lg, float4* __restrict__ sc,
                       float4* __restrict__ Ds, int writeDiag, int n) {
    int i = blockIdx.x * blockDim.x + threadIdx.x;
    int st = gridDim.x * blockDim.x;
    for (; i < n; i += st) {
        float4 x = lg[i];
        float m = fmaxf(fmaxf(x.x, x.y), fmaxf(x.z, x.w));
        float s = __expf(x.x - m) + __expf(x.y - m) + __expf(x.z - m) + __expf(x.w - m);
        float l = m + __logf(s);
        float4 r = make_float4(x.x - l, x.y - l, x.z - l, x.w - l);
        sc[i] = r;
        if (writeDiag) {
            int b = i >> 16;
            int rr = i & 65535;
            int t = rr >> 8;
            int v = rr & 255;
            Ds[(((size_t)b * SLABS + t + (v >> 2)) << 8) + v] = r;
        }
    }
}

// Kernel 3: permute diag-layout counts back to (b,t,v) output layout.
__global__ void k_perm(const float4* __restrict__ Dc, float4* __restrict__ out, int n) {
    int i = blockIdx.x * blockDim.x + threadIdx.x;
    int st = gridDim.x * blockDim.x;
    for (; i < n; i += st) {
        int b = i >> 16;
        int rr = i & 65535;
        int t = rr >> 8;
        int v = rr & 255;
        out[i] = Dc[(((size_t)b * SLABS + t + (v >> 2)) << 8) + v];
    }
}

// Kernel 2: anti-diagonal wavefront DP with dense (diag-layout) loads.
// 4 independent batches per block (one per wave, 4 SIMDs of one CU) so each
// wave's exp/shfl/waitcnt stalls are hidden by the other waves' ready work.
// Lane L owns columns 4L..4L+3, step s processes row t = s - L.
// For interior cells norm == alpha, so counts = exp(e - alpha): 3 exps per cell.
template <bool DIAG_STORE>
__global__ void __launch_bounds__(256) k_dp_diag(const float4* __restrict__ Ds,
                                                 float4* __restrict__ Dc,
                                                 float4* __restrict__ counts,
                                                 float* __restrict__ scalar_out) {
    const int wid = threadIdx.x >> 6;
    const int lane = threadIdx.x & 63;  // 0..63
    const int b = (blockIdx.x << 2) | wid;
    const int v0 = lane << 2;

    const float4* __restrict__ Dsb = Ds + (((size_t)b * SLABS) << 8) + v0;
    float4* __restrict__ Dcb = DIAG_STORE ? (Dc + (((size_t)b * SLABS) << 8) + v0) : nullptr;
    float4* __restrict__ crow = DIAG_STORE ? nullptr : (counts + (size_t)b * TT * VV + v0);

    // 4-deep prefetch ring over diag slabs
    float4 P0[4], P1[4], P2[4], P3[4];
    {
        const float4* p;
        p = Dsb;                  P0[0]=p[0]; P0[1]=p[1]; P0[2]=p[2]; P0[3]=p[3];
        p = Dsb + (1 << 8);       P1[0]=p[0]; P1[1]=p[1]; P1[2]=p[2]; P1[3]=p[3];
        p = Dsb + (2 << 8);       P2[0]=p[0]; P2[1]=p[1]; P2[2]=p[2]; P2[3]=p[3];
        p = Dsb + (3 << 8);       P3[0]=p[0]; P3[1]=p[1]; P3[2]=p[2]; P3[3]=p[3];
    }

    float aPrev[4] = { -INFINITY, -INFINITY, -INFINITY, -INFINITY };
    float leftPrev = -INFINITY;  // alpha[t-1][v0-1]
    float leftCur  = -INFINITY;  // alpha[t][v0-1]

    int s = 0;

#define STEP(BUF)                                                                 \
    {                                                                             \
        const int t = s - lane;                                                   \
        float4 c0 = BUF[0], c1 = BUF[1], c2 = BUF[2], c3 = BUF[3];                \
        { /* prefetch slab s+4 (clamped; pad slabs never consumed as real data) */\
            int sp = s + 4; sp = sp > SLABS - 1 ? SLABS - 1 : sp;                 \
            const float4* lp = Dsb + ((size_t)sp << 8);                           \
            BUF[0] = lp[0]; BUF[1] = lp[1]; BUF[2] = lp[2]; BUF[3] = lp[3];       \
        }                                                                         \
        float aPm1_0 = (lane == 0) ? -INFINITY : leftPrev;                        \
        float cv0 = lae(c0.x + aPrev[0], c0.z + aPm1_0);                          \
        float cv1 = lae(c1.x + aPrev[1], c1.z + aPrev[0]);                        \
        float cv2 = lae(c2.x + aPrev[2], c2.z + aPrev[1]);                        \
        float cv3 = lae(c3.x + aPrev[3], c3.z + aPrev[2]);                        \
        if (lane == 0) cv0 = c0.x + aPrev[0];   /* v==0: no sub term */           \
        if (t == 0) { /* row 0: alpha = [0, cumsum(ins[1:])] */                   \
            cv0 = (lane == 0) ? 0.0f : -INFINITY;                                 \
            cv1 = -INFINITY; cv2 = -INFINITY; cv3 = -INFINITY;                    \
        }                                                                         \
        float lc = (lane == 0) ? -INFINITY : leftCur;                             \
        float a0 = lae(lc + c0.y, cv0);                                           \
        float a1 = lae(a0 + c1.y, cv1);                                           \
        float a2 = lae(a1 + c2.y, cv2);                                           \
        float a3 = lae(a2 + c3.y, cv3);                                           \
        const bool active = (t >= 0) && (t < TT);                                 \
        if (DIAG_STORE || active) {                                               \
            const bool tE = (t <= 0) | (t >= TT - 1);                             \
            float aCm1[4] = { lc, a0, a1, a2 };                                   \
            float aPm1[4] = { aPm1_0, aPrev[0], aPrev[1], aPrev[2] };             \
            float aP[4]   = { aPrev[0], aPrev[1], aPrev[2], aPrev[3] };           \
            float aA[4]   = { a0, a1, a2, a3 };                                   \
            float4 sv[4]  = { c0, c1, c2, c3 };                                   \
            float4* cp = DIAG_STORE ? (Dcb + ((size_t)s << 8))                    \
                                    : (crow + (size_t)t * VV);                    \
            _Pragma("unroll")                                                     \
            for (int k = 0; k < 4; ++k) {                                         \
                const bool vE = (k == 0 && lane == 0) || (k == 3 && lane == 63);  \
                float w0 = __expf(aP[k]   + sv[k].x - aA[k]);                     \
                float w1 = __expf(aCm1[k] + sv[k].y - aA[k]);                     \
                float w2 = __expf(aPm1[k] + sv[k].z - aA[k]);                     \
                float4 o;                                                         \
                o.x = tE ? 0.0f : (vE ? 1.0f : w0);                               \
                o.y = vE ? 0.0f : (tE ? 1.0f : w1);                               \
                o.z = (tE || vE) ? 0.0f : w2;                                     \
                o.w = 0.0f;                                                       \
                cp[k] = o;                                                        \
            }                                                                     \
        }                                                                         \
        if ((t == TT - 1) && (lane == 63) && (b == 0)) scalar_out[0] = a3;        \
        aPrev[0] = a0; aPrev[1] = a1; aPrev[2] = a2; aPrev[3] = a3;               \
        leftPrev = leftCur;                                                       \
        leftCur = __shfl_up(a3, 1);                                               \
        ++s;                                                                      \
    }

    // 320 steps >= 319 needed (lane 63 finishes row 255 at s=318); 4x unrolled
    // so the ring index is compile-time static (no scratch).
#pragma unroll 1
    for (int it = 0; it < 80; ++it) {
        STEP(P0);
        STEP(P1);
        STEP(P2);
        STEP(P3);
    }
#undef STEP
}

// Fallback (round-2 kernel, scattered loads+stores) for tiny ws_size.
__global__ void __launch_bounds__(64) k_dp_legacy(const float4* __restrict__ scores,
                                                  float4* __restrict__ counts,
                                                  float* __restrict__ scalar_out) {
    const int b = blockIdx.x;
    const int lane = threadIdx.x;
    const int v0 = lane << 2;
    const float4* __restrict__ srow = scores + ((size_t)b * TT * VV + v0);
    float4* __restrict__ crow = counts + ((size_t)b * TT * VV + v0);
    float4 P0[4], P1[4], P2[4];
    {
        int r; const float4* p;
        r = 0 - lane; r = r < 0 ? 0 : r; p = srow + (size_t)r * VV;
        P0[0]=p[0]; P0[1]=p[1]; P0[2]=p[2]; P0[3]=p[3];
        r = 1 - lane; r = r < 0 ? 0 : r; p = srow + (size_t)r * VV;
        P1[0]=p[0]; P1[1]=p[1]; P1[2]=p[2]; P1[3]=p[3];
        r = 2 - lane; r = r < 0 ? 0 : r; p = srow + (size_t)r * VV;
        P2[0]=p[0]; P2[1]=p[1]; P2[2]=p[2]; P2[3]=p[3];
    }
    float aPrev[4] = { -INFINITY, -INFINITY, -INFINITY, -INFINITY };
    float leftPrev = -INFINITY, leftCur = -INFINITY;
    int s = 0;
#define STEPL(BUF)                                                                \
    {                                                                             \
        const int t = s - lane;                                                   \
        const bool active = (t >= 0) && (t < TT);                                 \
        float4 c0 = BUF[0], c1 = BUF[1], c2 = BUF[2], c3 = BUF[3];                \
        {                                                                         \
            int tp = t + 3; tp = tp < 0 ? 0 : tp; tp = tp > TT - 1 ? TT - 1 : tp; \
            const float4* lp = srow + (size_t)tp * VV;                            \
            BUF[0]=lp[0]; BUF[1]=lp[1]; BUF[2]=lp[2]; BUF[3]=lp[3];               \
        }                                                                         \
        float aPm1_0 = (lane == 0) ? -INFINITY : leftPrev;                        \
        float cv0 = lae(c0.x + aPrev[0], c0.z + aPm1_0);                          \
        float cv1 = lae(c1.x + aPrev[1], c1.z + aPrev[0]);                        \
        float cv2 = lae(c2.x + aPrev[2], c2.z + aPrev[1]);                        \
        float cv3 = lae(c3.x + aPrev[3], c3.z + aPrev[2]);                        \
        if (lane == 0) cv0 = c0.x + aPrev[0];                                     \
        if (t == 0) {                                                             \
            cv0 = (lane == 0) ? 0.0f : -INFINITY;                                 \
            cv1 = -INFINITY; cv2 = -INFINITY; cv3 = -INFINITY;                    \
        }                                                                         \
        float lc = (lane == 0) ? -INFINITY : leftCur;                             \
        float a0 = lae(lc + c0.y, cv0);                                           \
        float a1 = lae(a0 + c1.y, cv1);                                           \
        float a2 = lae(a1 + c2.y, cv2);                                           \
        float a3 = lae(a2 + c3.y, cv3);                                           \
        if (active) {                                                             \
            const bool tE = (t == 0) | (t == TT - 1);                             \
            float aCm1[4] = { lc, a0, a1, a2 };                                   \
            float aPm1[4] = { aPm1_0, aPrev[0], aPrev[1], aPrev[2] };             \
            float aP[4]   = { aPrev[0], aPrev[1], aPrev[2], aPrev[3] };           \
            float aA[4]   = { a0, a1, a2, a3 };                                   \
            float4 sv[4]  = { c0, c1, c2, c3 };                                   \
            float4* cp = crow + (size_t)t * VV;                                   \
            _Pragma("unroll")                                                     \
            for (int k = 0; k < 4; ++k) {                                         \
                const bool vE = (k == 0 && lane == 0) || (k == 3 && lane == 63);  \
                float w0 = __expf(aP[k]   + sv[k].x - aA[k]);                     \
                float w1 = __expf(aCm1[k] + sv[k].y - aA[k]);                     \
                float w2 = __expf(aPm1[k] + sv[k].z - aA[k]);                     \
                float4 o;                                                         \
                o.x = tE ? 0.0f : (vE ? 1.0f : w0);                               \
                o.y = vE ? 0.0f : (tE ? 1.0f : w1);                               \
                o.z = (tE || vE) ? 0.0f : w2;                                     \
                o.w = 0.0f;                                                       \
                cp[k] = o;                                                        \
            }                                                                     \
            if ((t == TT - 1) && (lane == 63) && (b == 0)) scalar_out[0] = a3;    \
        }                                                                         \
        aPrev[0]=a0; aPrev[1]=a1; aPrev[2]=a2; aPrev[3]=a3;                       \
        leftPrev = leftCur;                                                       \
        leftCur = __shfl_up(a3, 1);                                               \
        ++s;                                                                      \
    }
#pragma unroll 1
    for (int it = 0; it < 107; ++it) { STEPL(P0); STEPL(P1); STEPL(P2); }
#undef STEPL
}

extern "C" void kernel_launch(void* const* d_in, const int* in_sizes, int n_in,
                              void* d_out, int out_size, void* d_ws, size_t ws_size,
                              hipStream_t stream) {
    const float* logits = (const float*)d_in[0];
    float* out = (float*)d_out;
    const size_t ncell = (size_t)BB * TT * VV;  // 4,194,304 cells (each C=4)

    float4* scores = (float4*)out;                    // output 0: log_softmax
    float4* counts = (float4*)(out + ncell * 4);      // output 1: expected_counts
    float* scalar_out = out + ncell * 8;              // output 2: alpha[0,-1,-1]

    const size_t dbuf = ((size_t)BB * SLABS) << 12;   // 84,148,224 B per diag buffer
    float4* Ds = (float4*)d_ws;
    float4* Dc = (float4*)((char*)d_ws + dbuf);

    if (ws_size >= 2 * dbuf) {
        k_prep<<<2048, 256, 0, stream>>>((const float4*)logits, scores, Ds, 1, (int)ncell);
        k_dp_diag<true><<<16, 256, 0, stream>>>(Ds, Dc, counts, scalar_out);
        k_perm<<<2048, 256, 0, stream>>>(Dc, counts, (int)ncell);
    } else if (ws_size >= dbuf) {
        k_prep<<<2048, 256, 0, stream>>>((const float4*)logits, scores, Ds, 1, (int)ncell);
        k_dp_diag<false><<<16, 256, 0, stream>>>(Ds, nullptr, counts, scalar_out);
    } else {
        k_prep<<<2048, 256, 0, stream>>>((const float4*)logits, scores, nullptr, 0, (int)ncell);
        k_dp_legacy<<<BB, 64, 0, stream>>>(scores, counts, scalar_out);
    }
}

// Round 5
// 277.288 us; speedup vs baseline: 1.3774x; 1.3774x over previous
//
#include <hip/hip_runtime.h>
#include <math.h>

#define BB 64
#define TT 256
#define VV 256
#define SLABS 321            // s = t + v/4 in [0,318]; +2 pad for clamped prefetch
#define SLAB_F (SLABS * 256) // floats per batch per plane = 82176
#define PLANE ((size_t)BB * SLAB_F) // floats per plane = 5,255,424 (~21 MB)

// lean logaddexp: m + log1p(exp(-|x-y|)). NaN only when BOTH inputs are -inf,
// which happens only in the t<0 garbage triangle (never feeds a valid cell:
// every lane's first valid step consumes the left neighbor's t==0 fixup row).
__device__ __forceinline__ float lae2(float x, float y) {
    float m = fmaxf(x, y);
    float d = x - y;
    return m + __logf(1.0f + __expf(-fabsf(d)));
}

// Kernel 1: log_softmax over C=4 -> canonical scores (output 0) and, if wp,
// three SoA diag planes del/ins/sub with layout [b][s][v], s = t + v/4.
__global__ void k_prep(const float4* __restrict__ lg, float4* __restrict__ sc,
                       float* __restrict__ Dd, float* __restrict__ Di,
                       float* __restrict__ Du, int wp, int n) {
    int i = blockIdx.x * blockDim.x + threadIdx.x;
    int st = gridDim.x * blockDim.x;
    for (; i < n; i += st) {
        float4 x = lg[i];
        float m = fmaxf(fmaxf(x.x, x.y), fmaxf(x.z, x.w));
        float s = __expf(x.x - m) + __expf(x.y - m) + __expf(x.z - m) + __expf(x.w - m);
        float l = m + __logf(s);
        float4 r = make_float4(x.x - l, x.y - l, x.z - l, x.w - l);
        sc[i] = r;
        if (wp) {
            int b = i >> 16;
            int rr = i & 65535;
            int t = rr >> 8;
            int v = rr & 255;
            int pb = b * SLAB_F + (t + (v >> 2)) * 256 + v;
            Dd[pb] = r.x; Di[pb] = r.y; Du[pb] = r.z;
        }
    }
}

// Kernel 2: minimal serial DP. One wave per batch (64 CUs, 1 wave/CU — round 4
// showed colocation regresses on TA contention). Lane L owns columns 4L..4L+3;
// step s computes row t = s - L. Stores ONLY alpha (diag layout, 1 float/cell).
__global__ void __launch_bounds__(64) k_dp(const float* __restrict__ Dd,
                                           const float* __restrict__ Di,
                                           const float* __restrict__ Du,
                                           float* __restrict__ A,
                                           float* __restrict__ scalar_out) {
    const int b = blockIdx.x;
    const int lane = threadIdx.x;  // 0..63
    const size_t base = (size_t)b * SLAB_F + (lane << 2);

    const float4* __restrict__ pd = (const float4*)(Dd + base);
    const float4* __restrict__ pi = (const float4*)(Di + base);
    const float4* __restrict__ pu = (const float4*)(Du + base);
    float4* __restrict__ pa = (float4*)(A + base);
    // slab stride in float4 units:
    const int SS = 64;

    // 4-deep prefetch ring (statically indexed via 4x unroll)
    float4 d0, i0, u0, d1, i1, u1, d2, i2, u2, d3, i3, u3;
    d0 = pd[0 * SS]; i0 = pi[0 * SS]; u0 = pu[0 * SS];
    d1 = pd[1 * SS]; i1 = pi[1 * SS]; u1 = pu[1 * SS];
    d2 = pd[2 * SS]; i2 = pi[2 * SS]; u2 = pu[2 * SS];
    d3 = pd[3 * SS]; i3 = pi[3 * SS]; u3 = pu[3 * SS];

    float aP0 = -INFINITY, aP1 = -INFINITY, aP2 = -INFINITY, aP3 = -INFINITY;
    float leftPrev = -INFINITY;  // alpha[t-1][v0-1]
    float leftCur  = -INFINITY;  // alpha[t][v0-1]

    int s = 0;

#define STEP(DD, II, UU)                                                          \
    {                                                                             \
        const int t = s - lane;                                                   \
        float4 dl = DD, in = II, su = UU;                                         \
        { /* prefetch slab s+4 (clamped; pad slabs never consumed as real) */     \
            int sp = s + 4; sp = sp > SLABS - 1 ? SLABS - 1 : sp;                 \
            DD = pd[sp * SS]; II = pi[sp * SS]; UU = pu[sp * SS];                 \
        }                                                                         \
        float aPm1_0 = (lane == 0) ? -INFINITY : leftPrev;                        \
        float cv0 = lae2(dl.x + aP0, su.x + aPm1_0);                              \
        float cv1 = lae2(dl.y + aP1, su.y + aP0);                                 \
        float cv2 = lae2(dl.z + aP2, su.z + aP1);                                 \
        float cv3 = lae2(dl.w + aP3, su.w + aP2);                                 \
        if (lane == 0) cv0 = dl.x + aP0;   /* v==0: no sub term */                \
        if (t == 0) { /* row 0: alpha = [0, cumsum(ins[1:])] */                   \
            cv0 = (lane == 0) ? 0.0f : -INFINITY;                                 \
            cv1 = -INFINITY; cv2 = -INFINITY; cv3 = -INFINITY;                    \
        }                                                                         \
        float lc = (lane == 0) ? -INFINITY : leftCur;                             \
        float a0 = lae2(lc + in.x, cv0);                                          \
        float a1 = lae2(a0 + in.y, cv1);                                          \
        float a2 = lae2(a1 + in.z, cv2);                                          \
        float a3 = lae2(a2 + in.w, cv3);                                          \
        pa[s * SS] = make_float4(a0, a1, a2, a3);                                 \
        if ((t == TT - 1) && (lane == 63) && (b == 0)) scalar_out[0] = a3;        \
        aP0 = a0; aP1 = a1; aP2 = a2; aP3 = a3;                                   \
        leftPrev = leftCur;                                                       \
        leftCur = __shfl_up(a3, 1);                                               \
        ++s;                                                                      \
    }

    // 320 steps (lane 63 finishes row 255 at s=318); 4x unrolled for static ring.
#pragma unroll 1
    for (int it = 0; it < 80; ++it) {
        STEP(d0, i0, u0);
        STEP(d1, i1, u1);
        STEP(d2, i2, u2);
        STEP(d3, i3, u3);
    }
#undef STEP
}

// Kernel 3: full-occupancy counts. For interior cells norm == alpha, so
// counts = exp(a_neighbor + score - alpha); edges resolve to 0/1 by select
// (math validated rounds 2-4).
__global__ void k_counts(const float4* __restrict__ sc, const float* __restrict__ A,
                         float4* __restrict__ out, int n) {
    int i = blockIdx.x * blockDim.x + threadIdx.x;
    int st = gridDim.x * blockDim.x;
    for (; i < n; i += st) {
        int b = i >> 16;
        int rr = i & 65535;
        int t = rr >> 8;
        int v = rr & 255;
        int base = b * SLAB_F;
        int tm = t ? t - 1 : 0;
        int vm = v ? v - 1 : 0;
        float aA = A[base + (t  + (v  >> 2)) * 256 + v ];
        float aU = A[base + (tm + (v  >> 2)) * 256 + v ];
        float aL = A[base + (t  + (vm >> 2)) * 256 + vm];
        float aD = A[base + (tm + (vm >> 2)) * 256 + vm];
        float4 s = sc[i];
        float w0 = __expf(aU + s.x - aA);
        float w1 = __expf(aL + s.y - aA);
        float w2 = __expf(aD + s.z - aA);
        bool tE = (t == 0) | (t == TT - 1);
        bool vE = (v == 0) | (v == VV - 1);
        float4 o;
        o.x = tE ? 0.0f : (vE ? 1.0f : w0);
        o.y = vE ? 0.0f : (tE ? 1.0f : w1);
        o.z = (tE | vE) ? 0.0f : w2;
        o.w = 0.0f;
        out[i] = o;
    }
}

// Fallback for tiny ws: fused scattered DP (round-2 kernel, reads canonical scores).
__global__ void __launch_bounds__(64) k_dp_legacy(const float4* __restrict__ scores,
                                                  float4* __restrict__ counts,
                                                  float* __restrict__ scalar_out) {
    const int b = blockIdx.x;
    const int lane = threadIdx.x;
    const int v0 = lane << 2;
    const float4* __restrict__ srow = scores + ((size_t)b * TT * VV + v0);
    float4* __restrict__ crow = counts + ((size_t)b * TT * VV + v0);
    float4 P0[4], P1[4], P2[4];
    {
        int r; const float4* p;
        r = 0 - lane; r = r < 0 ? 0 : r; p = srow + (size_t)r * VV;
        P0[0]=p[0]; P0[1]=p[1]; P0[2]=p[2]; P0[3]=p[3];
        r = 1 - lane; r = r < 0 ? 0 : r; p = srow + (size_t)r * VV;
        P1[0]=p[0]; P1[1]=p[1]; P1[2]=p[2]; P1[3]=p[3];
        r = 2 - lane; r = r < 0 ? 0 : r; p = srow + (size_t)r * VV;
        P2[0]=p[0]; P2[1]=p[1]; P2[2]=p[2]; P2[3]=p[3];
    }
    float aPrev[4] = { -INFINITY, -INFINITY, -INFINITY, -INFINITY };
    float leftPrev = -INFINITY, leftCur = -INFINITY;
    int s = 0;
#define STEPL(BUF)                                                                \
    {                                                                             \
        const int t = s - lane;                                                   \
        const bool active = (t >= 0) && (t < TT);                                 \
        float4 c0 = BUF[0], c1 = BUF[1], c2 = BUF[2], c3 = BUF[3];                \
        {                                                                         \
            int tp = t + 3; tp = tp < 0 ? 0 : tp; tp = tp > TT - 1 ? TT - 1 : tp; \
            const float4* lp = srow + (size_t)tp * VV;                            \
            BUF[0]=lp[0]; BUF[1]=lp[1]; BUF[2]=lp[2]; BUF[3]=lp[3];               \
        }                                                                         \
        float aPm1_0 = (lane == 0) ? -INFINITY : leftPrev;                        \
        float cv0 = lae2(c0.x + aPrev[0], c0.z + aPm1_0);                         \
        float cv1 = lae2(c1.x + aPrev[1], c1.z + aPrev[0]);                       \
        float cv2 = lae2(c2.x + aPrev[2], c2.z + aPrev[1]);                       \
        float cv3 = lae2(c3.x + aPrev[3], c3.z + aPrev[2]);                       \
        if (lane == 0) cv0 = c0.x + aPrev[0];                                     \
        if (t == 0) {                                                             \
            cv0 = (lane == 0) ? 0.0f : -INFINITY;                                 \
            cv1 = -INFINITY; cv2 = -INFINITY; cv3 = -INFINITY;                    \
        }                                                                         \
        float lc = (lane == 0) ? -INFINITY : leftCur;                             \
        float a0 = lae2(lc + c0.y, cv0);                                          \
        float a1 = lae2(a0 + c1.y, cv1);                                          \
        float a2 = lae2(a1 + c2.y, cv2);                                          \
        float a3 = lae2(a2 + c3.y, cv3);                                          \
        if (active) {                                                             \
            const bool tE = (t == 0) | (t == TT - 1);                             \
            float aCm1[4] = { lc, a0, a1, a2 };                                   \
            float aPm1[4] = { aPm1_0, aPrev[0], aPrev[1], aPrev[2] };             \
            float aP[4]   = { aPrev[0], aPrev[1], aPrev[2], aPrev[3] };           \
            float aA[4]   = { a0, a1, a2, a3 };                                   \
            float4 sv[4]  = { c0, c1, c2, c3 };                                   \
            float4* cp = crow + (size_t)t * VV;                                   \
            _Pragma("unroll")                                                     \
            for (int k = 0; k < 4; ++k) {                                         \
                const bool vE = (k == 0 && lane == 0) || (k == 3 && lane == 63);  \
                float w0 = __expf(aP[k]   + sv[k].x - aA[k]);                     \
                float w1 = __expf(aCm1[k] + sv[k].y - aA[k]);                     \
                float w2 = __expf(aPm1[k] + sv[k].z - aA[k]);                     \
                float4 o;                                                         \
                o.x = tE ? 0.0f : (vE ? 1.0f : w0);                               \
                o.y = vE ? 0.0f : (tE ? 1.0f : w1);                               \
                o.z = (tE || vE) ? 0.0f : w2;                                     \
                o.w = 0.0f;                                                       \
                cp[k] = o;                                                        \
            }                                                                     \
            if ((t == TT - 1) && (lane == 63) && (b == 0)) scalar_out[0] = a3;    \
        }                                                                         \
        aPrev[0]=a0; aPrev[1]=a1; aPrev[2]=a2; aPrev[3]=a3;                       \
        leftPrev = leftCur;                                                       \
        leftCur = __shfl_up(a3, 1);                                               \
        ++s;                                                                      \
    }
#pragma unroll 1
    for (int it = 0; it < 107; ++it) { STEPL(P0); STEPL(P1); STEPL(P2); }
#undef STEPL
}

extern "C" void kernel_launch(void* const* d_in, const int* in_sizes, int n_in,
                              void* d_out, int out_size, void* d_ws, size_t ws_size,
                              hipStream_t stream) {
    const float* logits = (const float*)d_in[0];
    float* out = (float*)d_out;
    const size_t ncell = (size_t)BB * TT * VV;  // 4,194,304 cells (each C=4)

    float4* scores = (float4*)out;                    // output 0: log_softmax
    float4* counts = (float4*)(out + ncell * 4);      // output 1: expected_counts
    float* scalar_out = out + ncell * 8;              // output 2: alpha[0,-1,-1]

    float* Dd = (float*)d_ws;            // del plane  [BB][SLABS][256]
    float* Di = Dd + PLANE;              // ins plane
    float* Du = Di + PLANE;              // sub plane
    float* Aa = Du + PLANE;              // alpha      [BB][SLABS][256]

    if (ws_size >= 4 * PLANE * sizeof(float)) {
        k_prep<<<2048, 256, 0, stream>>>((const float4*)logits, scores, Dd, Di, Du, 1, (int)ncell);
        k_dp<<<BB, 64, 0, stream>>>(Dd, Di, Du, Aa, scalar_out);
        k_counts<<<2048, 256, 0, stream>>>(scores, Aa, counts, (int)ncell);
    } else {
        k_prep<<<2048, 256, 0, stream>>>((const float4*)logits, scores, nullptr, nullptr, nullptr, 0, (int)ncell);
        k_dp_legacy<<<BB, 64, 0, stream>>>(scores, counts, scalar_out);
    }
}

// Round 6
// 205.760 us; speedup vs baseline: 1.8563x; 1.3476x over previous
//
#include <hip/hip_runtime.h>
#include <math.h>

#define BB 64
#define TT 256
#define VV 256
#define SLABS 321            // s = t + v/4 in [0,318]; +2 pad for clamped prefetch
#define SLAB_F (SLABS * 256) // floats per batch per plane = 82176
#define PLANE ((size_t)BB * SLAB_F)       // floats per A/D/I/U plane (~21 MB)
#define EPLANE ((size_t)BB * SLABS * 64)  // ints in exponent plane (~5.3 MB)

// log-domain logaddexp for the legacy fallback only
__device__ __forceinline__ float lae2(float x, float y) {
    float m = fmaxf(x, y);
    float d = x - y;
    return m + __logf(1.0f + __expf(-fabsf(d)));
}

// Kernel 1: log_softmax over C=4 -> canonical scores (output 0) and, if wp,
// three SoA diag planes of PROBABILITIES del/ins/sub, layout [b][s][v], s=t+v/4.
__global__ void k_prep(const float4* __restrict__ lg, float4* __restrict__ sc,
                       float* __restrict__ Dd, float* __restrict__ Di,
                       float* __restrict__ Du, int wp, int n) {
    int i = blockIdx.x * blockDim.x + threadIdx.x;
    int st = gridDim.x * blockDim.x;
    for (; i < n; i += st) {
        float4 x = lg[i];
        float m = fmaxf(fmaxf(x.x, x.y), fmaxf(x.z, x.w));
        float e0 = __expf(x.x - m), e1 = __expf(x.y - m);
        float e2 = __expf(x.z - m), e3 = __expf(x.w - m);
        float ssum = e0 + e1 + e2 + e3;
        float l = m + __logf(ssum);
        sc[i] = make_float4(x.x - l, x.y - l, x.z - l, x.w - l);
        if (wp) {
            int b = i >> 16;
            int rr = i & 65535;
            int t = rr >> 8;
            int v = rr & 255;
            int pb = b * SLAB_F + (t + (v >> 2)) * 256 + v;
            float rcp = 1.0f / ssum;
            Dd[pb] = e0 * rcp; Di[pb] = e1 * rcp; Du[pb] = e2 * rcp;
        }
    }
}

// Kernel 2: serial anti-diagonal DP in the LINEAR (probability) domain — zero
// transcendentals. One wave per batch (1 wave/CU; colocation regressed, round 4).
// Lane L owns columns 4L..4L+3; step s computes row t = s - L.
// State: alpha[t][v] = A_k * 2^E (per-lane E, renormalized on A3 each step via
// exponent bit-extract + v_ldexp — exact). Cross-lane values adjusted by
// ldexp(x, E_src - E_dst). Recurrence: X_k = D_k*AP_k + U_k*AP_{k-1};
// A_k = A_{k-1}*I_k + X_k, split as A_k = B_k + lc*Q_k so only the last FMA
// waits on the shuffle. Garbage in the t<0 triangle (incl. NaN/inf) is killed
// at t==0: X:=0/1 by select, lc/E adopted from left's valid row-0, and the
// B-chain carries no cross-step state.
__global__ void __launch_bounds__(64) k_dp(const float* __restrict__ Pd,
                                           const float* __restrict__ Pi,
                                           const float* __restrict__ Pu,
                                           float* __restrict__ A,
                                           int* __restrict__ Ei,
                                           float* __restrict__ scalar_out) {
    const int b = blockIdx.x;
    const int lane = threadIdx.x;  // 0..63
    const bool l0 = (lane == 0);
    const size_t base = (size_t)b * SLAB_F + (lane << 2);

    const float4* __restrict__ pd = (const float4*)(Pd + base);
    const float4* __restrict__ pi = (const float4*)(Pi + base);
    const float4* __restrict__ pu = (const float4*)(Pu + base);
    float4* __restrict__ pa = (float4*)(A + base);
    int* __restrict__ pe = Ei + (size_t)b * SLABS * 64 + lane;
    const int SS = 64;  // slab stride in float4

    // 4-deep prefetch ring (statically indexed via 4x unroll)
    float4 d0, i0, u0, d1, i1, u1, d2, i2, u2, d3, i3, u3;
    d0 = pd[0 * SS]; i0 = pi[0 * SS]; u0 = pu[0 * SS];
    d1 = pd[1 * SS]; i1 = pi[1 * SS]; u1 = pu[1 * SS];
    d2 = pd[2 * SS]; i2 = pi[2 * SS]; u2 = pu[2 * SS];
    d3 = pd[3 * SS]; i3 = pi[3 * SS]; u3 = pu[3 * SS];

    float A0 = 0.0f, A1 = 0.0f, A2 = 0.0f, A3 = 0.0f;
    int   E  = 0;
    float LC = 0.0f, LP = 0.0f;   // left neighbor's A3 from steps s-1, s-2
    int   EC = 0,    EP = 0;      // matching exponents

    int s = 0;

#define STEP(DD, II, UU)                                                          \
    {                                                                             \
        const int t = s - lane;                                                   \
        const float4 dl = DD, in = II, su = UU;                                   \
        { /* prefetch slab s+4 (clamped; pads never feed valid cells) */          \
            int sp = s + 4; sp = sp > SLABS - 1 ? SLABS - 1 : sp;                 \
            DD = pd[sp * SS]; II = pi[sp * SS]; UU = pu[sp * SS];                 \
        }                                                                         \
        const bool isT0 = (t == 0);                                               \
        const int E_eff = isT0 ? (l0 ? 0 : EC) : E;                               \
        const float lc = l0 ? 0.0f : ldexpf(LC, EC - E_eff);                      \
        const float lp = l0 ? 0.0f : ldexpf(LP, EP - E_eff);                      \
        float X0 = dl.x * A0 + su.x * lp;                                         \
        float X1 = dl.y * A1 + su.y * A0;                                         \
        float X2 = dl.z * A2 + su.z * A1;                                         \
        float X3 = dl.w * A3 + su.w * A2;                                         \
        if (isT0) { X0 = l0 ? 1.0f : 0.0f; X1 = 0.0f; X2 = 0.0f; X3 = 0.0f; }     \
        const float B0 = X0;                                                      \
        const float B1 = fmaf(B0, in.y, X1);                                      \
        const float B2 = fmaf(B1, in.z, X2);                                      \
        const float B3 = fmaf(B2, in.w, X3);                                      \
        const float Q0 = in.x;                                                    \
        const float Q1 = Q0 * in.y;                                               \
        const float Q2 = Q1 * in.z;                                               \
        const float Q3 = Q2 * in.w;                                               \
        float nA0 = fmaf(lc, Q0, B0);                                             \
        float nA1 = fmaf(lc, Q1, B1);                                             \
        float nA2 = fmaf(lc, Q2, B2);                                             \
        float nA3 = fmaf(lc, Q3, B3);                                             \
        const int eb = (int)((__float_as_uint(nA3) >> 23) & 255u) - 126;          \
        const int En = E_eff + eb;                                                \
        nA0 = ldexpf(nA0, -eb);                                                   \
        nA1 = ldexpf(nA1, -eb);                                                   \
        nA2 = ldexpf(nA2, -eb);                                                   \
        nA3 = ldexpf(nA3, -eb);                                                   \
        pa[s * SS] = make_float4(nA0, nA1, nA2, nA3);                             \
        pe[s * 64] = En;                                                          \
        if ((t == TT - 1) && (lane == 63) && (b == 0))                            \
            scalar_out[0] = logf(nA3) + (float)En * 0.6931471805599453f;          \
        A0 = nA0; A1 = nA1; A2 = nA2; A3 = nA3; E = En;                           \
        LP = LC; EP = EC;                                                         \
        LC = __shfl_up(nA3, 1);                                                   \
        EC = __shfl_up(En, 1);                                                    \
        ++s;                                                                      \
    }

    // 320 steps (lane 63 finishes row 255 at s=318); 4x unrolled for static ring.
#pragma unroll 1
    for (int it = 0; it < 80; ++it) {
        STEP(d0, i0, u0);
        STEP(d1, i1, u1);
        STEP(d2, i2, u2);
        STEP(d3, i3, u3);
    }
#undef STEP
}

// Kernel 3: full-occupancy counts from (A, E) planes. For interior cells
// norm == alpha, so count = exp(s)·(A_nb/A_cell)·2^(E_nb-E_cell); edges by
// select (mask structure validated rounds 2-5).
__global__ void k_counts(const float4* __restrict__ sc, const float* __restrict__ A,
                         const int* __restrict__ Ei, float4* __restrict__ out, int n) {
    int i = blockIdx.x * blockDim.x + threadIdx.x;
    int st = gridDim.x * blockDim.x;
    for (; i < n; i += st) {
        int b = i >> 16;
        int rr = i & 65535;
        int t = rr >> 8;
        int v = rr & 255;
        int lane = v >> 2;
        int tm = t ? t - 1 : 0;
        int vm = v ? v - 1 : 0;
        int laneM = vm >> 2;
        size_t ab = (size_t)b * SLAB_F;
        size_t ebp = (size_t)b * SLABS * 64;
        int s0 = t + lane;
        int sU = tm + lane;
        int sL = t + laneM;
        int sD = tm + laneM;
        float AA = A[ab + (size_t)s0 * 256 + v];  int EA = Ei[ebp + s0 * 64 + lane];
        float AU = A[ab + (size_t)sU * 256 + v];  int EU = Ei[ebp + sU * 64 + lane];
        float AL = A[ab + (size_t)sL * 256 + vm]; int EL = Ei[ebp + sL * 64 + laneM];
        float AD = A[ab + (size_t)sD * 256 + vm]; int ED = Ei[ebp + sD * 64 + laneM];
        float4 sv = sc[i];
        float rA = 1.0f / AA;
        float w0 = ldexpf(__expf(sv.x) * AU * rA, EU - EA);
        float w1 = ldexpf(__expf(sv.y) * AL * rA, EL - EA);
        float w2 = ldexpf(__expf(sv.z) * AD * rA, ED - EA);
        bool tE = (t == 0) | (t == TT - 1);
        bool vE = (v == 0) | (v == VV - 1);
        float4 o;
        o.x = tE ? 0.0f : (vE ? 1.0f : w0);
        o.y = vE ? 0.0f : (tE ? 1.0f : w1);
        o.z = (tE | vE) ? 0.0f : w2;
        o.w = 0.0f;
        out[i] = o;
    }
}

// Fallback for tiny ws: fused scattered log-domain DP (validated round 2).
__global__ void __launch_bounds__(64) k_dp_legacy(const float4* __restrict__ scores,
                                                  float4* __restrict__ counts,
                                                  float* __restrict__ scalar_out) {
    const int b = blockIdx.x;
    const int lane = threadIdx.x;
    const int v0 = lane << 2;
    const float4* __restrict__ srow = scores + ((size_t)b * TT * VV + v0);
    float4* __restrict__ crow = counts + ((size_t)b * TT * VV + v0);
    float4 P0[4], P1[4], P2[4];
    {
        int r; const float4* p;
        r = 0 - lane; r = r < 0 ? 0 : r; p = srow + (size_t)r * VV;
        P0[0]=p[0]; P0[1]=p[1]; P0[2]=p[2]; P0[3]=p[3];
        r = 1 - lane; r = r < 0 ? 0 : r; p = srow + (size_t)r * VV;
        P1[0]=p[0]; P1[1]=p[1]; P1[2]=p[2]; P1[3]=p[3];
        r = 2 - lane; r = r < 0 ? 0 : r; p = srow + (size_t)r * VV;
        P2[0]=p[0]; P2[1]=p[1]; P2[2]=p[2]; P2[3]=p[3];
    }
    float aPrev[4] = { -INFINITY, -INFINITY, -INFINITY, -INFINITY };
    float leftPrev = -INFINITY, leftCur = -INFINITY;
    int s = 0;
#define STEPL(BUF)                                                                \
    {                                                                             \
        const int t = s - lane;                                                   \
        const bool active = (t >= 0) && (t < TT);                                 \
        float4 c0 = BUF[0], c1 = BUF[1], c2 = BUF[2], c3 = BUF[3];                \
        {                                                                         \
            int tp = t + 3; tp = tp < 0 ? 0 : tp; tp = tp > TT - 1 ? TT - 1 : tp; \
            const float4* lp = srow + (size_t)tp * VV;                            \
            BUF[0]=lp[0]; BUF[1]=lp[1]; BUF[2]=lp[2]; BUF[3]=lp[3];               \
        }                                                                         \
        float aPm1_0 = (lane == 0) ? -INFINITY : leftPrev;                        \
        float cv0 = lae2(c0.x + aPrev[0], c0.z + aPm1_0);                         \
        float cv1 = lae2(c1.x + aPrev[1], c1.z + aPrev[0]);                       \
        float cv2 = lae2(c2.x + aPrev[2], c2.z + aPrev[1]);                       \
        float cv3 = lae2(c3.x + aPrev[3], c3.z + aPrev[2]);                       \
        if (lane == 0) cv0 = c0.x + aPrev[0];                                     \
        if (t == 0) {                                                             \
            cv0 = (lane == 0) ? 0.0f : -INFINITY;                                 \
            cv1 = -INFINITY; cv2 = -INFINITY; cv3 = -INFINITY;                    \
        }                                                                         \
        float lc = (lane == 0) ? -INFINITY : leftCur;                             \
        float a0 = lae2(lc + c0.y, cv0);                                          \
        float a1 = lae2(a0 + c1.y, cv1);                                          \
        float a2 = lae2(a1 + c2.y, cv2);                                          \
        float a3 = lae2(a2 + c3.y, cv3);                                          \
        if (active) {                                                             \
            const bool tE = (t == 0) | (t == TT - 1);                             \
            float aCm1[4] = { lc, a0, a1, a2 };                                   \
            float aPm1[4] = { aPm1_0, aPrev[0], aPrev[1], aPrev[2] };             \
            float aP[4]   = { aPrev[0], aPrev[1], aPrev[2], aPrev[3] };           \
            float aA[4]   = { a0, a1, a2, a3 };                                   \
            float4 sv[4]  = { c0, c1, c2, c3 };                                   \
            float4* cp = crow + (size_t)t * VV;                                   \
            _Pragma("unroll")                                                     \
            for (int k = 0; k < 4; ++k) {                                         \
                const bool vE = (k == 0 && lane == 0) || (k == 3 && lane == 63);  \
                float w0 = __expf(aP[k]   + sv[k].x - aA[k]);                     \
                float w1 = __expf(aCm1[k] + sv[k].y - aA[k]);                     \
                float w2 = __expf(aPm1[k] + sv[k].z - aA[k]);                     \
                float4 o;                                                         \
                o.x = tE ? 0.0f : (vE ? 1.0f : w0);                               \
                o.y = vE ? 0.0f : (tE ? 1.0f : w1);                               \
                o.z = (tE || vE) ? 0.0f : w2;                                     \
                o.w = 0.0f;                                                       \
                cp[k] = o;                                                        \
            }                                                                     \
            if ((t == TT - 1) && (lane == 63) && (b == 0)) scalar_out[0] = a3;    \
        }                                                                         \
        aPrev[0]=a0; aPrev[1]=a1; aPrev[2]=a2; aPrev[3]=a3;                       \
        leftPrev = leftCur;                                                       \
        leftCur = __shfl_up(a3, 1);                                               \
        ++s;                                                                      \
    }
#pragma unroll 1
    for (int it = 0; it < 107; ++it) { STEPL(P0); STEPL(P1); STEPL(P2); }
#undef STEPL
}

extern "C" void kernel_launch(void* const* d_in, const int* in_sizes, int n_in,
                              void* d_out, int out_size, void* d_ws, size_t ws_size,
                              hipStream_t stream) {
    const float* logits = (const float*)d_in[0];
    float* out = (float*)d_out;
    const size_t ncell = (size_t)BB * TT * VV;  // 4,194,304 cells (each C=4)

    float4* scores = (float4*)out;                    // output 0: log_softmax
    float4* counts = (float4*)(out + ncell * 4);      // output 1: expected_counts
    float* scalar_out = out + ncell * 8;              // output 2: alpha[0,-1,-1]

    float* Pd = (float*)d_ws;            // del prob plane  [BB][SLABS][256]
    float* Pi = Pd + PLANE;              // ins prob plane
    float* Pu = Pi + PLANE;              // sub prob plane
    float* Aa = Pu + PLANE;              // alpha mantissa  [BB][SLABS][256]
    int*   Ee = (int*)(Aa + PLANE);      // alpha exponent  [BB][SLABS][64]

    if (ws_size >= (4 * PLANE + EPLANE) * 4) {
        k_prep<<<2048, 256, 0, stream>>>((const float4*)logits, scores, Pd, Pi, Pu, 1, (int)ncell);
        k_dp<<<BB, 64, 0, stream>>>(Pd, Pi, Pu, Aa, Ee, scalar_out);
        k_counts<<<2048, 256, 0, stream>>>(scores, Aa, Ee, counts, (int)ncell);
    } else {
        k_prep<<<2048, 256, 0, stream>>>((const float4*)logits, scores, nullptr, nullptr, nullptr, 0, (int)ncell);
        k_dp_legacy<<<BB, 64, 0, stream>>>(scores, counts, scalar_out);
    }
}

// Round 7
// 150.504 us; speedup vs baseline: 2.5378x; 1.3671x over previous
//
#include <hip/hip_runtime.h>
#include <math.h>

#define BB 64
#define TT 256
#define VV 256
#define SLABS 321            // slab s = t + v/4 in [0,318]; +2 pad for clamped prefetch
#define SLAB_F (SLABS * 256) // floats per batch per plane = 82176
#define PLANE ((size_t)BB * SLAB_F)       // floats per A/D/I/U plane (~21 MB)
#define EPLANE ((size_t)BB * SLABS * 64)  // ints in exponent plane (~5.3 MB)
#define NSLAB_W 319          // slabs 0..318 hold at least one valid (t,v)

// DPP wave_shr1: lane L <- lane L-1, single VALU op (lane 0 keeps own value;
// always masked by a lane-0 select at the use site). CDNA keeps GFX9 wave_shr1.
__device__ __forceinline__ float dpp_shr1_f(float x) {
    return __int_as_float(__builtin_amdgcn_update_dpp(
        __float_as_int(x), __float_as_int(x), 0x138, 0xF, 0xF, false));
}
__device__ __forceinline__ int dpp_shr1_i(int x) {
    return __builtin_amdgcn_update_dpp(x, x, 0x138, 0xF, 0xF, false);
}

// log-domain logaddexp for the legacy fallback only
__device__ __forceinline__ float lae2(float x, float y) {
    float m = fmaxf(x, y);
    float d = x - y;
    return m + __logf(1.0f + __expf(-fabsf(d)));
}

// Kernel 1 (diag-major): one block per (b, slab). Thread j owns v=j, t=s-(j>>2).
// Plane writes dense (1KB/wave/plane); logits read + scores write are whole-64B-line
// groups (4 threads x float4). Invalid-t lanes write prob 0 (cleans garbage triangle).
__global__ void __launch_bounds__(256) k_prep(const float4* __restrict__ lg,
                                              float4* __restrict__ sc,
                                              float* __restrict__ Dd,
                                              float* __restrict__ Di,
                                              float* __restrict__ Du) {
    int blk = blockIdx.x;
    int b = blk / NSLAB_W;
    int s = blk - b * NSLAB_W;
    int v = threadIdx.x;
    int t = s - (v >> 2);
    bool valid = (t >= 0) && (t < TT);
    int tc = valid ? t : 0;
    size_t ci = ((size_t)b << 16) | ((size_t)tc << 8) | (size_t)v;
    float4 x = lg[ci];
    float m = fmaxf(fmaxf(x.x, x.y), fmaxf(x.z, x.w));
    float e0 = __expf(x.x - m), e1 = __expf(x.y - m);
    float e2 = __expf(x.z - m), e3 = __expf(x.w - m);
    float ssum = e0 + e1 + e2 + e3;
    float l = m + __logf(ssum);
    if (valid) sc[ci] = make_float4(x.x - l, x.y - l, x.z - l, x.w - l);
    float rcp = valid ? (1.0f / ssum) : 0.0f;
    size_t pb = (size_t)b * SLAB_F + ((size_t)s << 8) + v;
    Dd[pb] = e0 * rcp; Di[pb] = e1 * rcp; Du[pb] = e2 * rcp;
}

// Kernel 2: serial anti-diagonal DP, linear (probability) domain, zero
// transcendentals; cross-lane via DPP wave_shr1 (round 6's ds_bpermute was on
// the 320-step critical path). One wave per batch (colocation regressed, r4).
// State alpha = A * 2^E per lane, renormalized on A3's exponent each step.
__global__ void __launch_bounds__(64) k_dp(const float* __restrict__ Pd,
                                           const float* __restrict__ Pi,
                                           const float* __restrict__ Pu,
                                           float* __restrict__ A,
                                           int* __restrict__ Ei,
                                           float* __restrict__ scalar_out) {
    const int b = blockIdx.x;
    const int lane = threadIdx.x;  // 0..63
    const bool l0 = (lane == 0);
    const size_t base = (size_t)b * SLAB_F + (lane << 2);

    const float4* __restrict__ pd = (const float4*)(Pd + base);
    const float4* __restrict__ pi = (const float4*)(Pi + base);
    const float4* __restrict__ pu = (const float4*)(Pu + base);
    float4* __restrict__ pa = (float4*)(A + base);
    int* __restrict__ pe = Ei + (size_t)b * SLABS * 64 + lane;
    const int SS = 64;  // slab stride in float4

    float4 d0, i0, u0, d1, i1, u1, d2, i2, u2, d3, i3, u3;
    d0 = pd[0 * SS]; i0 = pi[0 * SS]; u0 = pu[0 * SS];
    d1 = pd[1 * SS]; i1 = pi[1 * SS]; u1 = pu[1 * SS];
    d2 = pd[2 * SS]; i2 = pi[2 * SS]; u2 = pu[2 * SS];
    d3 = pd[3 * SS]; i3 = pi[3 * SS]; u3 = pu[3 * SS];

    float A0 = 0.0f, A1 = 0.0f, A2 = 0.0f, A3 = 0.0f;
    int   E  = 0;
    float LC = 0.0f, LP = 0.0f;   // left neighbor's A3 from steps s-1, s-2
    int   EC = 0,    EP = 0;

    int s = 0;

#define STEP(DD, II, UU)                                                          \
    {                                                                             \
        const int t = s - lane;                                                   \
        const float4 dl = DD, in = II, su = UU;                                   \
        { /* prefetch slab s+4 (clamped; pads never feed valid cells) */          \
            int sp = s + 4; sp = sp > SLABS - 1 ? SLABS - 1 : sp;                 \
            DD = pd[sp * SS]; II = pi[sp * SS]; UU = pu[sp * SS];                 \
        }                                                                         \
        const bool isT0 = (t == 0);                                               \
        const int E_eff = isT0 ? (l0 ? 0 : EC) : E;                               \
        const float lc = l0 ? 0.0f : ldexpf(LC, EC - E_eff);                      \
        const float lp = l0 ? 0.0f : ldexpf(LP, EP - E_eff);                      \
        float X0 = dl.x * A0 + su.x * lp;                                         \
        float X1 = dl.y * A1 + su.y * A0;                                         \
        float X2 = dl.z * A2 + su.z * A1;                                         \
        float X3 = dl.w * A3 + su.w * A2;                                         \
        if (isT0) { X0 = l0 ? 1.0f : 0.0f; X1 = 0.0f; X2 = 0.0f; X3 = 0.0f; }     \
        const float B0 = X0;                                                      \
        const float B1 = fmaf(B0, in.y, X1);                                      \
        const float B2 = fmaf(B1, in.z, X2);                                      \
        const float B3 = fmaf(B2, in.w, X3);                                      \
        const float Q0 = in.x;                                                    \
        const float Q1 = Q0 * in.y;                                               \
        const float Q2 = Q1 * in.z;                                               \
        const float Q3 = Q2 * in.w;                                               \
        float nA0 = fmaf(lc, Q0, B0);                                             \
        float nA1 = fmaf(lc, Q1, B1);                                             \
        float nA2 = fmaf(lc, Q2, B2);                                             \
        float nA3 = fmaf(lc, Q3, B3);                                             \
        const int eb = (int)((__float_as_uint(nA3) >> 23) & 255u) - 126;          \
        const int En = E_eff + eb;                                                \
        nA3 = ldexpf(nA3, -eb);                                                   \
        nA0 = ldexpf(nA0, -eb);                                                   \
        nA1 = ldexpf(nA1, -eb);                                                   \
        nA2 = ldexpf(nA2, -eb);                                                   \
        LP = LC; EP = EC;                                                         \
        LC = dpp_shr1_f(nA3);                                                     \
        EC = dpp_shr1_i(En);                                                      \
        pa[s * SS] = make_float4(nA0, nA1, nA2, nA3);                             \
        pe[s * 64] = En;                                                          \
        if ((t == TT - 1) && (lane == 63) && (b == 0))                            \
            scalar_out[0] = logf(nA3) + (float)En * 0.6931471805599453f;          \
        A0 = nA0; A1 = nA1; A2 = nA2; A3 = nA3; E = En;                           \
        ++s;                                                                      \
    }

#pragma unroll 1
    for (int it = 0; it < 80; ++it) {
        STEP(d0, i0, u0);
        STEP(d1, i1, u1);
        STEP(d2, i2, u2);
        STEP(d3, i3, u3);
    }
#undef STEP
}

// Kernel 3 (diag-major): wave handles one slab; lane L owns v-group 4L..4L+3,
// t = s - L. A-plane reads are dense slab loads (s, s-1, s-2) + 2 shuffles for
// the v-1 boundary; scores read / counts write are whole-64B-line groups.
// Interior: norm == alpha, count = exp(s)*(A_nb/A_cell)*2^(E_nb-E_cell).
__global__ void __launch_bounds__(256) k_counts(const float4* __restrict__ sc,
                                                const float* __restrict__ A,
                                                const int* __restrict__ Ei,
                                                float4* __restrict__ out) {
    int blk = blockIdx.x;
    int b = blk / 80;
    int sg = blk - b * 80;
    int s = (sg << 2) + (threadIdx.x >> 6);
    if (s >= NSLAB_W) return;  // whole-wave uniform exit
    int L = threadIdx.x & 63;
    int t = s - L;
    bool act = (t >= 0) && (t < TT);
    int tc = act ? t : 0;
    int sm1 = s > 0 ? s - 1 : 0;
    int sm2 = s > 1 ? s - 2 : 0;
    size_t ab = (size_t)b * SLAB_F;
    size_t ebp = (size_t)b * SLABS * 64;
    int v0 = L << 2;
    float4 AA = *(const float4*)(A + ab + ((size_t)s   << 8) + v0);
    float4 AU = *(const float4*)(A + ab + ((size_t)sm1 << 8) + v0);
    float4 AD = *(const float4*)(A + ab + ((size_t)sm2 << 8) + v0);
    int EA = Ei[ebp + s   * 64 + L];
    int EU = Ei[ebp + sm1 * 64 + L];
    int ED = Ei[ebp + sm2 * 64 + L];
    // boundary values from lane L-1 (all 64 lanes alive here)
    float aLm = dpp_shr1_f(AU.w);  // alpha[t][v0-1]
    int   eLm = dpp_shr1_i(EU);
    float aDm = dpp_shr1_f(AD.w);  // alpha[t-1][v0-1]
    int   eDm = dpp_shr1_i(ED);
    if (!act) return;

    const float4* sp4 = sc + (((size_t)b << 16) | ((size_t)tc << 8) | v0);
    float4* op4 = out + (((size_t)b << 16) | ((size_t)tc << 8) | v0);
    bool tE = (t == 0) | (t == TT - 1);

    float AAa[4] = { AA.x, AA.y, AA.z, AA.w };
    float AUa[4] = { AU.x, AU.y, AU.z, AU.w };
#pragma unroll
    for (int k = 0; k < 4; ++k) {
        int v = v0 + k;
        bool vE = (v == 0) | (v == VV - 1);
        float aAk = AAa[k];
        float aUk = AUa[k];
        float aLk = (k == 0) ? aLm : AAa[k - 1];
        int   eLk = (k == 0) ? eLm : EA;
        float aDk = (k == 0) ? aDm : AUa[k - 1];
        int   eDk = (k == 0) ? eDm : EU;
        float4 sv = sp4[k];
        float inv = 1.0f / aAk;
        float w0 = ldexpf(__expf(sv.x) * aUk * inv, EU - EA);
        float w1 = ldexpf(__expf(sv.y) * aLk * inv, eLk - EA);
        float w2 = ldexpf(__expf(sv.z) * aDk * inv, eDk - EA);
        float4 o;
        o.x = tE ? 0.0f : (vE ? 1.0f : w0);
        o.y = vE ? 0.0f : (tE ? 1.0f : w1);
        o.z = (tE | vE) ? 0.0f : w2;
        o.w = 0.0f;
        op4[k] = o;
    }
}

// Fallbacks for tiny ws: canonical log_softmax + fused scattered log-domain DP.
__global__ void k_prep_legacy(const float4* __restrict__ lg, float4* __restrict__ sc, int n) {
    int i = blockIdx.x * blockDim.x + threadIdx.x;
    int st = gridDim.x * blockDim.x;
    for (; i < n; i += st) {
        float4 x = lg[i];
        float m = fmaxf(fmaxf(x.x, x.y), fmaxf(x.z, x.w));
        float s = __expf(x.x - m) + __expf(x.y - m) + __expf(x.z - m) + __expf(x.w - m);
        float l = m + __logf(s);
        sc[i] = make_float4(x.x - l, x.y - l, x.z - l, x.w - l);
    }
}
__global__ void __launch_bounds__(64) k_dp_legacy(const float4* __restrict__ scores,
                                                  float4* __restrict__ counts,
                                                  float* __restrict__ scalar_out) {
    const int b = blockIdx.x;
    const int lane = threadIdx.x;
    const int v0 = lane << 2;
    const float4* __restrict__ srow = scores + ((size_t)b * TT * VV + v0);
    float4* __restrict__ crow = counts + ((size_t)b * TT * VV + v0);
    float4 P0[4], P1[4], P2[4];
    {
        int r; const float4* p;
        r = 0 - lane; r = r < 0 ? 0 : r; p = srow + (size_t)r * VV;
        P0[0]=p[0]; P0[1]=p[1]; P0[2]=p[2]; P0[3]=p[3];
        r = 1 - lane; r = r < 0 ? 0 : r; p = srow + (size_t)r * VV;
        P1[0]=p[0]; P1[1]=p[1]; P1[2]=p[2]; P1[3]=p[3];
        r = 2 - lane; r = r < 0 ? 0 : r; p = srow + (size_t)r * VV;
        P2[0]=p[0]; P2[1]=p[1]; P2[2]=p[2]; P2[3]=p[3];
    }
    float aPrev[4] = { -INFINITY, -INFINITY, -INFINITY, -INFINITY };
    float leftPrev = -INFINITY, leftCur = -INFINITY;
    int s = 0;
#define STEPL(BUF)                                                                \
    {                                                                             \
        const int t = s - lane;                                                   \
        const bool active = (t >= 0) && (t < TT);                                 \
        float4 c0 = BUF[0], c1 = BUF[1], c2 = BUF[2], c3 = BUF[3];                \
        {                                                                         \
            int tp = t + 3; tp = tp < 0 ? 0 : tp; tp = tp > TT - 1 ? TT - 1 : tp; \
            const float4* lp = srow + (size_t)tp * VV;                            \
            BUF[0]=lp[0]; BUF[1]=lp[1]; BUF[2]=lp[2]; BUF[3]=lp[3];               \
        }                                                                         \
        float aPm1_0 = (lane == 0) ? -INFINITY : leftPrev;                        \
        float cv0 = lae2(c0.x + aPrev[0], c0.z + aPm1_0);                         \
        float cv1 = lae2(c1.x + aPrev[1], c1.z + aPrev[0]);                       \
        float cv2 = lae2(c2.x + aPrev[2], c2.z + aPrev[1]);                       \
        float cv3 = lae2(c3.x + aPrev[3], c3.z + aPrev[2]);                       \
        if (lane == 0) cv0 = c0.x + aPrev[0];                                     \
        if (t == 0) {                                                             \
            cv0 = (lane == 0) ? 0.0f : -INFINITY;                                 \
            cv1 = -INFINITY; cv2 = -INFINITY; cv3 = -INFINITY;                    \
        }                                                                         \
        float lc = (lane == 0) ? -INFINITY : leftCur;                             \
        float a0 = lae2(lc + c0.y, cv0);                                          \
        float a1 = lae2(a0 + c1.y, cv1);                                          \
        float a2 = lae2(a1 + c2.y, cv2);                                          \
        float a3 = lae2(a2 + c3.y, cv3);                                          \
        if (active) {                                                             \
            const bool tE = (t == 0) | (t == TT - 1);                             \
            float aCm1[4] = { lc, a0, a1, a2 };                                   \
            float aPm1[4] = { aPm1_0, aPrev[0], aPrev[1], aPrev[2] };             \
            float aP[4]   = { aPrev[0], aPrev[1], aPrev[2], aPrev[3] };           \
            float aA[4]   = { a0, a1, a2, a3 };                                   \
            float4 sv[4]  = { c0, c1, c2, c3 };                                   \
            float4* cp = crow + (size_t)t * VV;                                   \
            _Pragma("unroll")                                                     \
            for (int k = 0; k < 4; ++k) {                                         \
                const bool vE = (k == 0 && lane == 0) || (k == 3 && lane == 63);  \
                float w0 = __expf(aP[k]   + sv[k].x - aA[k]);                     \
                float w1 = __expf(aCm1[k] + sv[k].y - aA[k]);                     \
                float w2 = __expf(aPm1[k] + sv[k].z - aA[k]);                     \
                float4 o;                                                         \
                o.x = tE ? 0.0f : (vE ? 1.0f : w0);                               \
                o.y = vE ? 0.0f : (tE ? 1.0f : w1);                               \
                o.z = (tE || vE) ? 0.0f : w2;                                     \
                o.w = 0.0f;                                                       \
                cp[k] = o;                                                        \
            }                                                                     \
            if ((t == TT - 1) && (lane == 63) && (b == 0)) scalar_out[0] = a3;    \
        }                                                                         \
        aPrev[0]=a0; aPrev[1]=a1; aPrev[2]=a2; aPrev[3]=a3;                       \
        leftPrev = leftCur;                                                       \
        leftCur = __shfl_up(a3, 1);                                               \
        ++s;                                                                      \
    }
#pragma unroll 1
    for (int it = 0; it < 107; ++it) { STEPL(P0); STEPL(P1); STEPL(P2); }
#undef STEPL
}

extern "C" void kernel_launch(void* const* d_in, const int* in_sizes, int n_in,
                              void* d_out, int out_size, void* d_ws, size_t ws_size,
                              hipStream_t stream) {
    const float* logits = (const float*)d_in[0];
    float* out = (float*)d_out;
    const size_t ncell = (size_t)BB * TT * VV;  // 4,194,304 cells (each C=4)

    float4* scores = (float4*)out;                    // output 0: log_softmax
    float4* counts = (float4*)(out + ncell * 4);      // output 1: expected_counts
    float* scalar_out = out + ncell * 8;              // output 2: alpha[0,-1,-1]

    float* Pd = (float*)d_ws;            // del prob plane  [BB][SLABS][256]
    float* Pi = Pd + PLANE;              // ins prob plane
    float* Pu = Pi + PLANE;              // sub prob plane
    float* Aa = Pu + PLANE;              // alpha mantissa  [BB][SLABS][256]
    int*   Ee = (int*)(Aa + PLANE);      // alpha exponent  [BB][SLABS][64]

    if (ws_size >= (4 * PLANE + EPLANE) * 4) {
        k_prep<<<BB * NSLAB_W, 256, 0, stream>>>((const float4*)logits, scores, Pd, Pi, Pu);
        k_dp<<<BB, 64, 0, stream>>>(Pd, Pi, Pu, Aa, Ee, scalar_out);
        k_counts<<<BB * 80, 256, 0, stream>>>(scores, Aa, Ee, counts);
    } else {
        k_prep_legacy<<<2048, 256, 0, stream>>>((const float4*)logits, scores, (int)ncell);
        k_dp_legacy<<<BB, 64, 0, stream>>>(scores, counts, scalar_out);
    }
}

// Round 8
// 142.914 us; speedup vs baseline: 2.6726x; 1.0531x over previous
//
#include <hip/hip_runtime.h>
#include <math.h>

#define BB 64
#define TT 256
#define VV 256
#define SLABS 321            // slab s = t + v/4 in [0,318]; +2 pad for clamped prefetch
#define SLAB_F (SLABS * 256) // floats per batch per plane = 82176
#define PLANE ((size_t)BB * SLAB_F)       // floats per A/D/I/U plane (~21 MB)
#define EPLANE ((size_t)BB * SLABS * 64)  // ints in exponent plane (~5.3 MB)
#define NSLAB_W 319          // slabs 0..318 hold at least one valid (t,v)

// DPP wave_shr1: lane L <- lane L-1, single VALU op (wave-local; lane 0 keeps
// own value and is always masked by a lane-0 select at the use site).
__device__ __forceinline__ float dpp_shr1_f(float x) {
    return __int_as_float(__builtin_amdgcn_update_dpp(
        __float_as_int(x), __float_as_int(x), 0x138, 0xF, 0xF, false));
}
__device__ __forceinline__ int dpp_shr1_i(int x) {
    return __builtin_amdgcn_update_dpp(x, x, 0x138, 0xF, 0xF, false);
}

// log-domain logaddexp for the legacy fallback only
__device__ __forceinline__ float lae2(float x, float y) {
    float m = fmaxf(x, y);
    float d = x - y;
    return m + __logf(1.0f + __expf(-fabsf(d)));
}

// Kernel 1 (diag-major): one block per (b, slab). Thread j owns v=j, t=s-(j>>2).
// Plane writes dense (1KB/wave/plane); logits read + scores write are whole-64B-line
// groups. Invalid-t lanes write prob 0 (cleans the garbage triangle).
__global__ void __launch_bounds__(256) k_prep(const float4* __restrict__ lg,
                                              float4* __restrict__ sc,
                                              float* __restrict__ Dd,
                                              float* __restrict__ Di,
                                              float* __restrict__ Du) {
    int blk = blockIdx.x;
    int b = blk / NSLAB_W;
    int s = blk - b * NSLAB_W;
    int v = threadIdx.x;
    int t = s - (v >> 2);
    bool valid = (t >= 0) && (t < TT);
    int tc = valid ? t : 0;
    size_t ci = ((size_t)b << 16) | ((size_t)tc << 8) | (size_t)v;
    float4 x = lg[ci];
    float m = fmaxf(fmaxf(x.x, x.y), fmaxf(x.z, x.w));
    float e0 = __expf(x.x - m), e1 = __expf(x.y - m);
    float e2 = __expf(x.z - m), e3 = __expf(x.w - m);
    float ssum = e0 + e1 + e2 + e3;
    float l = m + __logf(ssum);
    if (valid) sc[ci] = make_float4(x.x - l, x.y - l, x.z - l, x.w - l);
    float rcp = valid ? (1.0f / ssum) : 0.0f;
    size_t pb = (size_t)b * SLAB_F + ((size_t)s << 8) + v;
    Dd[pb] = e0 * rcp; Di[pb] = e1 * rcp; Du[pb] = e2 * rcp;
}

// Kernel 2: serial anti-diagonal DP, linear (probability) domain, zero
// transcendentals, DPP cross-lane. TWO waves per block = two independent
// batches per CU: all vmem is now dense (16-line) so the round-4 TA-serialization
// mechanism is gone, and the second wave hides the first's residual stalls.
__global__ void __launch_bounds__(128) k_dp(const float* __restrict__ Pd,
                                            const float* __restrict__ Pi,
                                            const float* __restrict__ Pu,
                                            float* __restrict__ A,
                                            int* __restrict__ Ei,
                                            float* __restrict__ scalar_out) {
    const int b = (blockIdx.x << 1) | (threadIdx.x >> 6);
    const int lane = threadIdx.x & 63;  // wave-local 0..63
    const bool l0 = (lane == 0);
    const size_t base = (size_t)b * SLAB_F + (lane << 2);

    const float4* __restrict__ pd = (const float4*)(Pd + base);
    const float4* __restrict__ pi = (const float4*)(Pi + base);
    const float4* __restrict__ pu = (const float4*)(Pu + base);
    float4* __restrict__ pa = (float4*)(A + base);
    int* __restrict__ pe = Ei + (size_t)b * SLABS * 64 + lane;
    const int SS = 64;  // slab stride in float4

    float4 d0, i0, u0, d1, i1, u1, d2, i2, u2, d3, i3, u3;
    d0 = pd[0 * SS]; i0 = pi[0 * SS]; u0 = pu[0 * SS];
    d1 = pd[1 * SS]; i1 = pi[1 * SS]; u1 = pu[1 * SS];
    d2 = pd[2 * SS]; i2 = pi[2 * SS]; u2 = pu[2 * SS];
    d3 = pd[3 * SS]; i3 = pi[3 * SS]; u3 = pu[3 * SS];

    float A0 = 0.0f, A1 = 0.0f, A2 = 0.0f, A3 = 0.0f;
    int   E  = 0;
    float LC = 0.0f, LP = 0.0f;   // left neighbor's A3 from steps s-1, s-2
    int   EC = 0,    EP = 0;

    int s = 0;

#define STEP(DD, II, UU)                                                          \
    {                                                                             \
        const int t = s - lane;                                                   \
        const float4 dl = DD, in = II, su = UU;                                   \
        { /* prefetch slab s+4 (clamped; pads never feed valid cells) */          \
            int sp = s + 4; sp = sp > SLABS - 1 ? SLABS - 1 : sp;                 \
            DD = pd[sp * SS]; II = pi[sp * SS]; UU = pu[sp * SS];                 \
        }                                                                         \
        const bool isT0 = (t == 0);                                               \
        const int E_eff = isT0 ? (l0 ? 0 : EC) : E;                               \
        const float lc = l0 ? 0.0f : ldexpf(LC, EC - E_eff);                      \
        const float lp = l0 ? 0.0f : ldexpf(LP, EP - E_eff);                      \
        float X0 = dl.x * A0 + su.x * lp;                                         \
        float X1 = dl.y * A1 + su.y * A0;                                         \
        float X2 = dl.z * A2 + su.z * A1;                                         \
        float X3 = dl.w * A3 + su.w * A2;                                         \
        if (isT0) { X0 = l0 ? 1.0f : 0.0f; X1 = 0.0f; X2 = 0.0f; X3 = 0.0f; }     \
        const float B0 = X0;                                                      \
        const float B1 = fmaf(B0, in.y, X1);                                      \
        const float B2 = fmaf(B1, in.z, X2);                                      \
        const float B3 = fmaf(B2, in.w, X3);                                      \
        const float Q0 = in.x;                                                    \
        const float Q1 = Q0 * in.y;                                               \
        const float Q2 = Q1 * in.z;                                               \
        const float Q3 = Q2 * in.w;                                               \
        float nA0 = fmaf(lc, Q0, B0);                                             \
        float nA1 = fmaf(lc, Q1, B1);                                             \
        float nA2 = fmaf(lc, Q2, B2);                                             \
        float nA3 = fmaf(lc, Q3, B3);                                             \
        const int eb = (int)((__float_as_uint(nA3) >> 23) & 255u) - 126;          \
        const int En = E_eff + eb;                                                \
        nA3 = ldexpf(nA3, -eb);                                                   \
        nA0 = ldexpf(nA0, -eb);                                                   \
        nA1 = ldexpf(nA1, -eb);                                                   \
        nA2 = ldexpf(nA2, -eb);                                                   \
        LP = LC; EP = EC;                                                         \
        LC = dpp_shr1_f(nA3);                                                     \
        EC = dpp_shr1_i(En);                                                      \
        pa[s * SS] = make_float4(nA0, nA1, nA2, nA3);                             \
        pe[s * 64] = En;                                                          \
        if ((t == TT - 1) && (lane == 63) && (b == 0))                            \
            scalar_out[0] = logf(nA3) + (float)En * 0.6931471805599453f;          \
        A0 = nA0; A1 = nA1; A2 = nA2; A3 = nA3; E = En;                           \
        ++s;                                                                      \
    }

#pragma unroll 1
    for (int it = 0; it < 80; ++it) {
        STEP(d0, i0, u0);
        STEP(d1, i1, u1);
        STEP(d2, i2, u2);
        STEP(d3, i3, u3);
    }
#undef STEP
}

// Kernel 3 (diag-major): wave handles one slab; lane L owns v-group 4L..4L+3.
// Reads prob PLANES (dense diag; exp(score) == prob exactly) — zero
// transcendentals. A-slab reads dense (s, s-1, s-2) + DPP for the v-1 boundary.
// Interior: norm == alpha, count = prob * (A_nb/A_cell) * 2^(E_nb-E_cell).
__global__ void __launch_bounds__(256) k_counts(const float* __restrict__ Pd,
                                                const float* __restrict__ Pi,
                                                const float* __restrict__ Pu,
                                                const float* __restrict__ A,
                                                const int* __restrict__ Ei,
                                                float4* __restrict__ out) {
    int blk = blockIdx.x;
    int b = blk / 80;
    int sg = blk - b * 80;
    int s = (sg << 2) + (threadIdx.x >> 6);
    if (s >= NSLAB_W) return;  // whole-wave uniform exit
    int L = threadIdx.x & 63;
    int t = s - L;
    bool act = (t >= 0) && (t < TT);
    int tc = act ? t : 0;
    int sm1 = s > 0 ? s - 1 : 0;
    int sm2 = s > 1 ? s - 2 : 0;
    size_t ab = (size_t)b * SLAB_F;
    size_t ebp = (size_t)b * SLABS * 64;
    int v0 = L << 2;
    float4 AA = *(const float4*)(A + ab + ((size_t)s   << 8) + v0);
    float4 AU = *(const float4*)(A + ab + ((size_t)sm1 << 8) + v0);
    float4 AD = *(const float4*)(A + ab + ((size_t)sm2 << 8) + v0);
    float4 pd4 = *(const float4*)(Pd + ab + ((size_t)s << 8) + v0);
    float4 pi4 = *(const float4*)(Pi + ab + ((size_t)s << 8) + v0);
    float4 pu4 = *(const float4*)(Pu + ab + ((size_t)s << 8) + v0);
    int EA = Ei[ebp + s   * 64 + L];
    int EU = Ei[ebp + sm1 * 64 + L];
    int ED = Ei[ebp + sm2 * 64 + L];
    // boundary values from lane L-1 (all 64 lanes alive here)
    float aLm = dpp_shr1_f(AU.w);  // alpha[t][v0-1]
    int   eLm = dpp_shr1_i(EU);
    float aDm = dpp_shr1_f(AD.w);  // alpha[t-1][v0-1]
    int   eDm = dpp_shr1_i(ED);
    if (!act) return;

    float4* op4 = out + (((size_t)b << 16) | ((size_t)tc << 8) | v0);
    bool tE = (t == 0) | (t == TT - 1);

    float AAa[4] = { AA.x, AA.y, AA.z, AA.w };
    float AUa[4] = { AU.x, AU.y, AU.z, AU.w };
    float PDa[4] = { pd4.x, pd4.y, pd4.z, pd4.w };
    float PIa[4] = { pi4.x, pi4.y, pi4.z, pi4.w };
    float PUa[4] = { pu4.x, pu4.y, pu4.z, pu4.w };
#pragma unroll
    for (int k = 0; k < 4; ++k) {
        int v = v0 + k;
        bool vE = (v == 0) | (v == VV - 1);
        float aAk = AAa[k];
        float aUk = AUa[k];
        float aLk = (k == 0) ? aLm : AAa[k - 1];
        int   eLk = (k == 0) ? eLm : EA;
        float aDk = (k == 0) ? aDm : AUa[k - 1];
        int   eDk = (k == 0) ? eDm : EU;
        float inv = 1.0f / aAk;
        float w0 = ldexpf(PDa[k] * aUk * inv, EU - EA);
        float w1 = ldexpf(PIa[k] * aLk * inv, eLk - EA);
        float w2 = ldexpf(PUa[k] * aDk * inv, eDk - EA);
        float4 o;
        o.x = tE ? 0.0f : (vE ? 1.0f : w0);
        o.y = vE ? 0.0f : (tE ? 1.0f : w1);
        o.z = (tE | vE) ? 0.0f : w2;
        o.w = 0.0f;
        op4[k] = o;
    }
}

// Fallbacks for tiny ws: canonical log_softmax + fused scattered log-domain DP.
__global__ void k_prep_legacy(const float4* __restrict__ lg, float4* __restrict__ sc, int n) {
    int i = blockIdx.x * blockDim.x + threadIdx.x;
    int st = gridDim.x * blockDim.x;
    for (; i < n; i += st) {
        float4 x = lg[i];
        float m = fmaxf(fmaxf(x.x, x.y), fmaxf(x.z, x.w));
        float s = __expf(x.x - m) + __expf(x.y - m) + __expf(x.z - m) + __expf(x.w - m);
        float l = m + __logf(s);
        sc[i] = make_float4(x.x - l, x.y - l, x.z - l, x.w - l);
    }
}
__global__ void __launch_bounds__(64) k_dp_legacy(const float4* __restrict__ scores,
                                                  float4* __restrict__ counts,
                                                  float* __restrict__ scalar_out) {
    const int b = blockIdx.x;
    const int lane = threadIdx.x;
    const int v0 = lane << 2;
    const float4* __restrict__ srow = scores + ((size_t)b * TT * VV + v0);
    float4* __restrict__ crow = counts + ((size_t)b * TT * VV + v0);
    float4 P0[4], P1[4], P2[4];
    {
        int r; const float4* p;
        r = 0 - lane; r = r < 0 ? 0 : r; p = srow + (size_t)r * VV;
        P0[0]=p[0]; P0[1]=p[1]; P0[2]=p[2]; P0[3]=p[3];
        r = 1 - lane; r = r < 0 ? 0 : r; p = srow + (size_t)r * VV;
        P1[0]=p[0]; P1[1]=p[1]; P1[2]=p[2]; P1[3]=p[3];
        r = 2 - lane; r = r < 0 ? 0 : r; p = srow + (size_t)r * VV;
        P2[0]=p[0]; P2[1]=p[1]; P2[2]=p[2]; P2[3]=p[3];
    }
    float aPrev[4] = { -INFINITY, -INFINITY, -INFINITY, -INFINITY };
    float leftPrev = -INFINITY, leftCur = -INFINITY;
    int s = 0;
#define STEPL(BUF)                                                                \
    {                                                                             \
        const int t = s - lane;                                                   \
        const bool active = (t >= 0) && (t < TT);                                 \
        float4 c0 = BUF[0], c1 = BUF[1], c2 = BUF[2], c3 = BUF[3];                \
        {                                                                         \
            int tp = t + 3; tp = tp < 0 ? 0 : tp; tp = tp > TT - 1 ? TT - 1 : tp; \
            const float4* lp = srow + (size_t)tp * VV;                            \
            BUF[0]=lp[0]; BUF[1]=lp[1]; BUF[2]=lp[2]; BUF[3]=lp[3];               \
        }                                                                         \
        float aPm1_0 = (lane == 0) ? -INFINITY : leftPrev;                        \
        float cv0 = lae2(c0.x + aPrev[0], c0.z + aPm1_0);                         \
        float cv1 = lae2(c1.x + aPrev[1], c1.z + aPrev[0]);                       \
        float cv2 = lae2(c2.x + aPrev[2], c2.z + aPrev[1]);                       \
        float cv3 = lae2(c3.x + aPrev[3], c3.z + aPrev[2]);                       \
        if (lane == 0) cv0 = c0.x + aPrev[0];                                     \
        if (t == 0) {                                                             \
            cv0 = (lane == 0) ? 0.0f : -INFINITY;                                 \
            cv1 = -INFINITY; cv2 = -INFINITY; cv3 = -INFINITY;                    \
        }                                                                         \
        float lc = (lane == 0) ? -INFINITY : leftCur;                             \
        float a0 = lae2(lc + c0.y, cv0);                                          \
        float a1 = lae2(a0 + c1.y, cv1);                                          \
        float a2 = lae2(a1 + c2.y, cv2);                                          \
        float a3 = lae2(a2 + c3.y, cv3);                                          \
        if (active) {                                                             \
            const bool tE = (t == 0) | (t == TT - 1);                             \
            float aCm1[4] = { lc, a0, a1, a2 };                                   \
            float aPm1[4] = { aPm1_0, aPrev[0], aPrev[1], aPrev[2] };             \
            float aP[4]   = { aPrev[0], aPrev[1], aPrev[2], aPrev[3] };           \
            float aA[4]   = { a0, a1, a2, a3 };                                   \
            float4 sv[4]  = { c0, c1, c2, c3 };                                   \
            float4* cp = crow + (size_t)t * VV;                                   \
            _Pragma("unroll")                                                     \
            for (int k = 0; k < 4; ++k) {                                         \
                const bool vE = (k == 0 && lane == 0) || (k == 3 && lane == 63);  \
                float w0 = __expf(aP[k]   + sv[k].x - aA[k]);                     \
                float w1 = __expf(aCm1[k] + sv[k].y - aA[k]);                     \
                float w2 = __expf(aPm1[k] + sv[k].z - aA[k]);                     \
                float4 o;                                                         \
                o.x = tE ? 0.0f : (vE ? 1.0f : w0);                               \
                o.y = vE ? 0.0f : (tE ? 1.0f : w1);                               \
                o.z = (tE || vE) ? 0.0f : w2;                                     \
                o.w = 0.0f;                                                       \
                cp[k] = o;                                                        \
            }                                                                     \
            if ((t == TT - 1) && (lane == 63) && (b == 0)) scalar_out[0] = a3;    \
        }                                                                         \
        aPrev[0]=a0; aPrev[1]=a1; aPrev[2]=a2; aPrev[3]=a3;                       \
        leftPrev = leftCur;                                                       \
        leftCur = __shfl_up(a3, 1);                                               \
        ++s;                                                                      \
    }
#pragma unroll 1
    for (int it = 0; it < 107; ++it) { STEPL(P0); STEPL(P1); STEPL(P2); }
#undef STEPL
}

extern "C" void kernel_launch(void* const* d_in, const int* in_sizes, int n_in,
                              void* d_out, int out_size, void* d_ws, size_t ws_size,
                              hipStream_t stream) {
    const float* logits = (const float*)d_in[0];
    float* out = (float*)d_out;
    const size_t ncell = (size_t)BB * TT * VV;  // 4,194,304 cells (each C=4)

    float4* scores = (float4*)out;                    // output 0: log_softmax
    float4* counts = (float4*)(out + ncell * 4);      // output 1: expected_counts
    float* scalar_out = out + ncell * 8;              // output 2: alpha[0,-1,-1]

    float* Pd = (float*)d_ws;            // del prob plane  [BB][SLABS][256]
    float* Pi = Pd + PLANE;              // ins prob plane
    float* Pu = Pi + PLANE;              // sub prob plane
    float* Aa = Pu + PLANE;              // alpha mantissa  [BB][SLABS][256]
    int*   Ee = (int*)(Aa + PLANE);      // alpha exponent  [BB][SLABS][64]

    if (ws_size >= (4 * PLANE + EPLANE) * 4) {
        k_prep<<<BB * NSLAB_W, 256, 0, stream>>>((const float4*)logits, scores, Pd, Pi, Pu);
        k_dp<<<BB / 2, 128, 0, stream>>>(Pd, Pi, Pu, Aa, Ee, scalar_out);
        k_counts<<<BB * 80, 256, 0, stream>>>(Pd, Pi, Pu, Aa, Ee, counts);
    } else {
        k_prep_legacy<<<2048, 256, 0, stream>>>((const float4*)logits, scores, (int)ncell);
        k_dp_legacy<<<BB, 64, 0, stream>>>(scores, counts, scalar_out);
    }
}

// Round 9
// 122.154 us; speedup vs baseline: 3.1268x; 1.1699x over previous
//
#include <hip/hip_runtime.h>
#include <math.h>

#define BB 64
#define TT 256
#define VV 256
#define SLABS 321            // slab s = t + v/4 in [0,318]; +2 pad for clamped prefetch
#define SLAB_F (SLABS * 256) // floats per batch per plane = 82176
#define PLANE ((size_t)BB * SLAB_F)       // floats per A/D/I/U plane (~21 MB)
#define EPLANE ((size_t)BB * SLABS * 64)  // ints in exponent plane (~5.3 MB)
#define NSLAB_W 319          // slabs 0..318 hold at least one valid (t,v)

// DPP wave_shr1: lane L <- lane L-1, single VALU op (wave-local; lane 0 keeps
// own value and is always masked by a lane-0 select at the use site).
__device__ __forceinline__ float dpp_shr1_f(float x) {
    return __int_as_float(__builtin_amdgcn_update_dpp(
        __float_as_int(x), __float_as_int(x), 0x138, 0xF, 0xF, false));
}
__device__ __forceinline__ int dpp_shr1_i(int x) {
    return __builtin_amdgcn_update_dpp(x, x, 0x138, 0xF, 0xF, false);
}

// log-domain logaddexp for the legacy fallback only
__device__ __forceinline__ float lae2(float x, float y) {
    float m = fmaxf(x, y);
    float d = x - y;
    return m + __logf(1.0f + __expf(-fabsf(d)));
}

// Kernel 1 (diag-major): one block per (b, slab). Thread j owns v=j, t=s-(j>>2).
// Plane writes dense (1KB/wave/plane); logits read + scores write are whole-64B-line
// groups. Invalid-t lanes write prob 0 (cleans the garbage triangle).
__global__ void __launch_bounds__(256) k_prep(const float4* __restrict__ lg,
                                              float4* __restrict__ sc,
                                              float* __restrict__ Dd,
                                              float* __restrict__ Di,
                                              float* __restrict__ Du) {
    int blk = blockIdx.x;
    int b = blk / NSLAB_W;
    int s = blk - b * NSLAB_W;
    int v = threadIdx.x;
    int t = s - (v >> 2);
    bool valid = (t >= 0) && (t < TT);
    int tc = valid ? t : 0;
    size_t ci = ((size_t)b << 16) | ((size_t)tc << 8) | (size_t)v;
    float4 x = lg[ci];
    float m = fmaxf(fmaxf(x.x, x.y), fmaxf(x.z, x.w));
    float e0 = __expf(x.x - m), e1 = __expf(x.y - m);
    float e2 = __expf(x.z - m), e3 = __expf(x.w - m);
    float ssum = e0 + e1 + e2 + e3;
    float l = m + __logf(ssum);
    if (valid) sc[ci] = make_float4(x.x - l, x.y - l, x.z - l, x.w - l);
    float rcp = valid ? (1.0f / ssum) : 0.0f;
    size_t pb = (size_t)b * SLAB_F + ((size_t)s << 8) + v;
    Dd[pb] = e0 * rcp; Di[pb] = e1 * rcp; Du[pb] = e2 * rcp;
}

// Kernel 2: serial anti-diagonal DP, linear (probability) domain, zero
// transcendentals, DPP cross-lane, 2 independent batches per CU (r8 measured
// best), and an 8-DEEP register prefetch ring: r8's budget shows ~450 cy/step
// of exposed LLC latency with the 4-deep ring — 8 slabs in flight cover
// ~8x step-time >= ~600-900 cy cross-XCD latency.
__global__ void __launch_bounds__(128) k_dp(const float* __restrict__ Pd,
                                            const float* __restrict__ Pi,
                                            const float* __restrict__ Pu,
                                            float* __restrict__ A,
                                            int* __restrict__ Ei,
                                            float* __restrict__ scalar_out) {
    const int b = (blockIdx.x << 1) | (threadIdx.x >> 6);
    const int lane = threadIdx.x & 63;  // wave-local 0..63
    const bool l0 = (lane == 0);
    const size_t base = (size_t)b * SLAB_F + (lane << 2);

    const float4* __restrict__ pd = (const float4*)(Pd + base);
    const float4* __restrict__ pi = (const float4*)(Pi + base);
    const float4* __restrict__ pu = (const float4*)(Pu + base);
    float4* __restrict__ pa = (float4*)(A + base);
    int* __restrict__ pe = Ei + (size_t)b * SLABS * 64 + lane;
    const int SS = 64;  // slab stride in float4

    // 8-deep prefetch ring (statically indexed via 8x unroll)
    float4 d0,d1,d2,d3,d4,d5,d6,d7;
    float4 i0,i1,i2,i3,i4,i5,i6,i7;
    float4 u0,u1,u2,u3,u4,u5,u6,u7;
    d0 = pd[0*SS]; i0 = pi[0*SS]; u0 = pu[0*SS];
    d1 = pd[1*SS]; i1 = pi[1*SS]; u1 = pu[1*SS];
    d2 = pd[2*SS]; i2 = pi[2*SS]; u2 = pu[2*SS];
    d3 = pd[3*SS]; i3 = pi[3*SS]; u3 = pu[3*SS];
    d4 = pd[4*SS]; i4 = pi[4*SS]; u4 = pu[4*SS];
    d5 = pd[5*SS]; i5 = pi[5*SS]; u5 = pu[5*SS];
    d6 = pd[6*SS]; i6 = pi[6*SS]; u6 = pu[6*SS];
    d7 = pd[7*SS]; i7 = pi[7*SS]; u7 = pu[7*SS];

    float A0 = 0.0f, A1 = 0.0f, A2 = 0.0f, A3 = 0.0f;
    int   E  = 0;
    float LC = 0.0f, LP = 0.0f;   // left neighbor's A3 from steps s-1, s-2
    int   EC = 0,    EP = 0;
    float sA3 = 0.0f;             // saved state at s==318 for scalar_out
    int   sEn = 0;

    int s = 0;

#define STEP(DD, II, UU)                                                          \
    {                                                                             \
        const int t = s - lane;                                                   \
        const float4 dl = DD, in = II, su = UU;                                   \
        { /* prefetch slab s+8 (clamped; pads never feed valid cells) */          \
            int sp = s + 8; sp = sp > SLABS - 1 ? SLABS - 1 : sp;                 \
            DD = pd[sp * SS]; II = pi[sp * SS]; UU = pu[sp * SS];                 \
        }                                                                         \
        const bool isT0 = (t == 0);                                               \
        const int E_eff = isT0 ? (l0 ? 0 : EC) : E;                               \
        const float lc = l0 ? 0.0f : ldexpf(LC, EC - E_eff);                      \
        const float lp = l0 ? 0.0f : ldexpf(LP, EP - E_eff);                      \
        float X0 = dl.x * A0 + su.x * lp;                                         \
        float X1 = dl.y * A1 + su.y * A0;                                         \
        float X2 = dl.z * A2 + su.z * A1;                                         \
        float X3 = dl.w * A3 + su.w * A2;                                         \
        if (isT0) { X0 = l0 ? 1.0f : 0.0f; X1 = 0.0f; X2 = 0.0f; X3 = 0.0f; }     \
        const float B0 = X0;                                                      \
        const float B1 = fmaf(B0, in.y, X1);                                      \
        const float B2 = fmaf(B1, in.z, X2);                                      \
        const float B3 = fmaf(B2, in.w, X3);                                      \
        const float Q0 = in.x;                                                    \
        const float Q1 = Q0 * in.y;                                               \
        const float Q2 = Q1 * in.z;                                               \
        const float Q3 = Q2 * in.w;                                               \
        float nA0 = fmaf(lc, Q0, B0);                                             \
        float nA1 = fmaf(lc, Q1, B1);                                             \
        float nA2 = fmaf(lc, Q2, B2);                                             \
        float nA3 = fmaf(lc, Q3, B3);                                             \
        const int eb = (int)((__float_as_uint(nA3) >> 23) & 255u) - 126;          \
        const int En = E_eff + eb;                                                \
        nA3 = ldexpf(nA3, -eb);                                                   \
        nA0 = ldexpf(nA0, -eb);                                                   \
        nA1 = ldexpf(nA1, -eb);                                                   \
        nA2 = ldexpf(nA2, -eb);                                                   \
        LP = LC; EP = EC;                                                         \
        LC = dpp_shr1_f(nA3);                                                     \
        EC = dpp_shr1_i(En);                                                      \
        pa[s * SS] = make_float4(nA0, nA1, nA2, nA3);                             \
        pe[s * 64] = En;                                                          \
        if (s == TT + 62) { sA3 = nA3; sEn = En; }  /* lane63: t==255 */          \
        A0 = nA0; A1 = nA1; A2 = nA2; A3 = nA3; E = En;                           \
        ++s;                                                                      \
    }

    // 320 steps (lane 63 finishes row 255 at s=318); 8x unrolled for static ring.
#pragma unroll 1
    for (int it = 0; it < 40; ++it) {
        STEP(d0, i0, u0);
        STEP(d1, i1, u1);
        STEP(d2, i2, u2);
        STEP(d3, i3, u3);
        STEP(d4, i4, u4);
        STEP(d5, i5, u5);
        STEP(d6, i6, u6);
        STEP(d7, i7, u7);
    }
#undef STEP

    if ((b == 0) && (lane == 63))
        scalar_out[0] = logf(sA3) + (float)sEn * 0.6931471805599453f;
}

// Kernel 3 (diag-major): wave handles one slab; lane L owns v-group 4L..4L+3.
// Reads prob PLANES (dense diag; exp(score) == prob exactly) — zero
// transcendentals. A-slab reads dense (s, s-1, s-2) + DPP for the v-1 boundary.
// Interior: norm == alpha, count = prob * (A_nb/A_cell) * 2^(E_nb-E_cell).
__global__ void __launch_bounds__(256) k_counts(const float* __restrict__ Pd,
                                                const float* __restrict__ Pi,
                                                const float* __restrict__ Pu,
                                                const float* __restrict__ A,
                                                const int* __restrict__ Ei,
                                                float4* __restrict__ out) {
    int blk = blockIdx.x;
    int b = blk / 80;
    int sg = blk - b * 80;
    int s = (sg << 2) + (threadIdx.x >> 6);
    if (s >= NSLAB_W) return;  // whole-wave uniform exit
    int L = threadIdx.x & 63;
    int t = s - L;
    bool act = (t >= 0) && (t < TT);
    int tc = act ? t : 0;
    int sm1 = s > 0 ? s - 1 : 0;
    int sm2 = s > 1 ? s - 2 : 0;
    size_t ab = (size_t)b * SLAB_F;
    size_t ebp = (size_t)b * SLABS * 64;
    int v0 = L << 2;
    float4 AA = *(const float4*)(A + ab + ((size_t)s   << 8) + v0);
    float4 AU = *(const float4*)(A + ab + ((size_t)sm1 << 8) + v0);
    float4 AD = *(const float4*)(A + ab + ((size_t)sm2 << 8) + v0);
    float4 pd4 = *(const float4*)(Pd + ab + ((size_t)s << 8) + v0);
    float4 pi4 = *(const float4*)(Pi + ab + ((size_t)s << 8) + v0);
    float4 pu4 = *(const float4*)(Pu + ab + ((size_t)s << 8) + v0);
    int EA = Ei[ebp + s   * 64 + L];
    int EU = Ei[ebp + sm1 * 64 + L];
    int ED = Ei[ebp + sm2 * 64 + L];
    // boundary values from lane L-1 (all 64 lanes alive here)
    float aLm = dpp_shr1_f(AU.w);  // alpha[t][v0-1]
    int   eLm = dpp_shr1_i(EU);
    float aDm = dpp_shr1_f(AD.w);  // alpha[t-1][v0-1]
    int   eDm = dpp_shr1_i(ED);
    if (!act) return;

    float4* op4 = out + (((size_t)b << 16) | ((size_t)tc << 8) | v0);
    bool tE = (t == 0) | (t == TT - 1);

    float AAa[4] = { AA.x, AA.y, AA.z, AA.w };
    float AUa[4] = { AU.x, AU.y, AU.z, AU.w };
    float PDa[4] = { pd4.x, pd4.y, pd4.z, pd4.w };
    float PIa[4] = { pi4.x, pi4.y, pi4.z, pi4.w };
    float PUa[4] = { pu4.x, pu4.y, pu4.z, pu4.w };
#pragma unroll
    for (int k = 0; k < 4; ++k) {
        int v = v0 + k;
        bool vE = (v == 0) | (v == VV - 1);
        float aAk = AAa[k];
        float aUk = AUa[k];
        float aLk = (k == 0) ? aLm : AAa[k - 1];
        int   eLk = (k == 0) ? eLm : EA;
        float aDk = (k == 0) ? aDm : AUa[k - 1];
        int   eDk = (k == 0) ? eDm : EU;
        float inv = 1.0f / aAk;
        float w0 = ldexpf(PDa[k] * aUk * inv, EU - EA);
        float w1 = ldexpf(PIa[k] * aLk * inv, eLk - EA);
        float w2 = ldexpf(PUa[k] * aDk * inv, eDk - EA);
        float4 o;
        o.x = tE ? 0.0f : (vE ? 1.0f : w0);
        o.y = vE ? 0.0f : (tE ? 1.0f : w1);
        o.z = (tE | vE) ? 0.0f : w2;
        o.w = 0.0f;
        op4[k] = o;
    }
}

// Fallbacks for tiny ws: canonical log_softmax + fused scattered log-domain DP.
__global__ void k_prep_legacy(const float4* __restrict__ lg, float4* __restrict__ sc, int n) {
    int i = blockIdx.x * blockDim.x + threadIdx.x;
    int st = gridDim.x * blockDim.x;
    for (; i < n; i += st) {
        float4 x = lg[i];
        float m = fmaxf(fmaxf(x.x, x.y), fmaxf(x.z, x.w));
        float s = __expf(x.x - m) + __expf(x.y - m) + __expf(x.z - m) + __expf(x.w - m);
        float l = m + __logf(s);
        sc[i] = make_float4(x.x - l, x.y - l, x.z - l, x.w - l);
    }
}
__global__ void __launch_bounds__(64) k_dp_legacy(const float4* __restrict__ scores,
                                                  float4* __restrict__ counts,
                                                  float* __restrict__ scalar_out) {
    const int b = blockIdx.x;
    const int lane = threadIdx.x;
    const int v0 = lane << 2;
    const float4* __restrict__ srow = scores + ((size_t)b * TT * VV + v0);
    float4* __restrict__ crow = counts + ((size_t)b * TT * VV + v0);
    float4 P0[4], P1[4], P2[4];
    {
        int r; const float4* p;
        r = 0 - lane; r = r < 0 ? 0 : r; p = srow + (size_t)r * VV;
        P0[0]=p[0]; P0[1]=p[1]; P0[2]=p[2]; P0[3]=p[3];
        r = 1 - lane; r = r < 0 ? 0 : r; p = srow + (size_t)r * VV;
        P1[0]=p[0]; P1[1]=p[1]; P1[2]=p[2]; P1[3]=p[3];
        r = 2 - lane; r = r < 0 ? 0 : r; p = srow + (size_t)r * VV;
        P2[0]=p[0]; P2[1]=p[1]; P2[2]=p[2]; P2[3]=p[3];
    }
    float aPrev[4] = { -INFINITY, -INFINITY, -INFINITY, -INFINITY };
    float leftPrev = -INFINITY, leftCur = -INFINITY;
    int s = 0;
#define STEPL(BUF)                                                                \
    {                                                                             \
        const int t = s - lane;                                                   \
        const bool active = (t >= 0) && (t < TT);                                 \
        float4 c0 = BUF[0], c1 = BUF[1], c2 = BUF[2], c3 = BUF[3];                \
        {                                                                         \
            int tp = t + 3; tp = tp < 0 ? 0 : tp; tp = tp > TT - 1 ? TT - 1 : tp; \
            const float4* lp = srow + (size_t)tp * VV;                            \
            BUF[0]=lp[0]; BUF[1]=lp[1]; BUF[2]=lp[2]; BUF[3]=lp[3];               \
        }                                                                         \
        float aPm1_0 = (lane == 0) ? -INFINITY : leftPrev;                        \
        float cv0 = lae2(c0.x + aPrev[0], c0.z + aPm1_0);                         \
        float cv1 = lae2(c1.x + aPrev[1], c1.z + aPrev[0]);                       \
        float cv2 = lae2(c2.x + aPrev[2], c2.z + aPrev[1]);                       \
        float cv3 = lae2(c3.x + aPrev[3], c3.z + aPrev[2]);                       \
        if (lane == 0) cv0 = c0.x + aPrev[0];                                     \
        if (t == 0) {                                                             \
            cv0 = (lane == 0) ? 0.0f : -INFINITY;                                 \
            cv1 = -INFINITY; cv2 = -INFINITY; cv3 = -INFINITY;                    \
        }                                                                         \
        float lc = (lane == 0) ? -INFINITY : leftCur;                             \
        float a0 = lae2(lc + c0.y, cv0);                                          \
        float a1 = lae2(a0 + c1.y, cv1);                                          \
        float a2 = lae2(a1 + c2.y, cv2);                                          \
        float a3 = lae2(a2 + c3.y, cv3);                                          \
        if (active) {                                                             \
            const bool tE = (t == 0) | (t == TT - 1);                             \
            float aCm1[4] = { lc, a0, a1, a2 };                                   \
            float aPm1[4] = { aPm1_0, aPrev[0], aPrev[1], aPrev[2] };             \
            float aP[4]   = { aPrev[0], aPrev[1], aPrev[2], aPrev[3] };           \
            float aA[4]   = { a0, a1, a2, a3 };                                   \
            float4 sv[4]  = { c0, c1, c2, c3 };                                   \
            float4* cp = crow + (size_t)t * VV;                                   \
            _Pragma("unroll")                                                     \
            for (int k = 0; k < 4; ++k) {                                         \
                const bool vE = (k == 0 && lane == 0) || (k == 3 && lane == 63);  \
                float w0 = __expf(aP[k]   + sv[k].x - aA[k]);                     \
                float w1 = __expf(aCm1[k] + sv[k].y - aA[k]);                     \
                float w2 = __expf(aPm1[k] + sv[k].z - aA[k]);                     \
                float4 o;                                                         \
                o.x = tE ? 0.0f : (vE ? 1.0f : w0);                               \
                o.y = vE ? 0.0f : (tE ? 1.0f : w1);                               \
                o.z = (tE || vE) ? 0.0f : w2;                                     \
                o.w = 0.0f;                                                       \
                cp[k] = o;                                                        \
            }                                                                     \
            if ((t == TT - 1) && (lane == 63) && (b == 0)) scalar_out[0] = a3;    \
        }                                                                         \
        aPrev[0]=a0; aPrev[1]=a1; aPrev[2]=a2; aPrev[3]=a3;                       \
        leftPrev = leftCur;                                                       \
        leftCur = __shfl_up(a3, 1);                                               \
        ++s;                                                                      \
    }
#pragma unroll 1
    for (int it = 0; it < 107; ++it) { STEPL(P0); STEPL(P1); STEPL(P2); }
#undef STEPL
}

extern "C" void kernel_launch(void* const* d_in, const int* in_sizes, int n_in,
                              void* d_out, int out_size, void* d_ws, size_t ws_size,
                              hipStream_t stream) {
    const float* logits = (const float*)d_in[0];
    float* out = (float*)d_out;
    const size_t ncell = (size_t)BB * TT * VV;  // 4,194,304 cells (each C=4)

    float4* scores = (float4*)out;                    // output 0: log_softmax
    float4* counts = (float4*)(out + ncell * 4);      // output 1: expected_counts
    float* scalar_out = out + ncell * 8;              // output 2: alpha[0,-1,-1]

    float* Pd = (float*)d_ws;            // del prob plane  [BB][SLABS][256]
    float* Pi = Pd + PLANE;              // ins prob plane
    float* Pu = Pi + PLANE;              // sub prob plane
    float* Aa = Pu + PLANE;              // alpha mantissa  [BB][SLABS][256]
    int*   Ee = (int*)(Aa + PLANE);      // alpha exponent  [BB][SLABS][64]

    if (ws_size >= (4 * PLANE + EPLANE) * 4) {
        k_prep<<<BB * NSLAB_W, 256, 0, stream>>>((const float4*)logits, scores, Pd, Pi, Pu);
        k_dp<<<BB / 2, 128, 0, stream>>>(Pd, Pi, Pu, Aa, Ee, scalar_out);
        k_counts<<<BB * 80, 256, 0, stream>>>(Pd, Pi, Pu, Aa, Ee, counts);
    } else {
        k_prep_legacy<<<2048, 256, 0, stream>>>((const float4*)logits, scores, (int)ncell);
        k_dp_legacy<<<BB, 64, 0, stream>>>(scores, counts, scalar_out);
    }
}